// Round 14
// baseline (274.130 us; speedup 1.0000x reference)
//
#include <hip/hip_runtime.h>
#include <hip/hip_bf16.h>

typedef __hip_bfloat16 bf16;
typedef short s8v __attribute__((ext_vector_type(8)));   // 8 bf16 = 4 VGPR MFMA frag
typedef short s4v __attribute__((ext_vector_type(4)));   // 4 bf16 = 8B packed store
typedef float f4v __attribute__((ext_vector_type(4)));   // 4 fp32 MFMA acc

#define DEVI __device__ __forceinline__

DEVI float cvt(float x){ return x; }
DEVI float cvt(bf16 x){ return __bfloat162float(x); }

DEVI void stg(float* p, float v){ *p = v; }
DEVI void stg(bf16* p, float v){ *p = __float2bfloat16(v); }

DEVI float gelu_exact(float x){
  return 0.5f*x*(1.0f + erff(x*0.70710678118654752440f));
}

// problem constants
constexpr int B_ = 2, C_ = 128, H_ = 56, W_ = 56, N_ = 3136, NH_ = 4, D_ = 32, HF_ = 341;
constexpr int ROWS_ = B_*N_;             // 6272
constexpr int KF2 = 352;                 // fc2 K padded 341 -> 352 (11*32)
constexpr int GQ_ = NH_*B_*N_;           // 25088 (bh*N + n)
constexpr int FW = 512;                  // fused qkv+sr width (q 0..128 | kv 128..384 | sr 384..512)
constexpr int KSP = 8;                   // attention key splits
constexpr int SPLIT = 384;               // keys per split (6 tiles; last split gets 448)
constexpr int NTILE = 392;               // LN tiles (6272/16)
constexpr float LOG2E = 1.4426950408889634f;
constexpr float E8L2  = 11.541560327111707f;   // 8*log2(e); exp(s-8) = exp2(s*log2e - E8L2)

// ---------------- tiled plane->row LayerNorm (16 rows x 128 ch per block) ----------
DEVI void ln_tile_body(int tile, int t, const float* __restrict__ x,
                       const float* __restrict__ w, const float* __restrict__ bia,
                       bf16* __restrict__ y, float* sm /*128*17*/, float* st /*32*/)
{
  int b = tile / 196, nb = (tile % 196) * 16;
  // phase 1: load 16 rows x 128 ch, thread (c,half) -> 8 consecutive n (two float4)
  {
    int c = t >> 1, half = t & 1;
    const float* xp = x + ((long)b*C_ + c)*N_ + nb + half*8;
    f4v v0 = *(const f4v*)xp;
    f4v v1 = *(const f4v*)(xp + 4);
    #pragma unroll
    for (int j=0;j<4;j++){
      sm[c*17 + half*8 + j    ] = v0[j];
      sm[c*17 + half*8 + 4 + j] = v1[j];
    }
  }
  __syncthreads();
  // phase 2: row stats; 16 threads per row, each sums 8 channels, xor-reduce low 4 bits
  {
    int i = t >> 4, k = t & 15;
    float s = 0.f, ss = 0.f;
    #pragma unroll
    for (int u=0;u<8;u++){
      float v = sm[(k + u*16)*17 + i];
      s += v; ss = fmaf(v,v,ss);
    }
    #pragma unroll
    for (int off=1; off<16; off<<=1){
      s  += __shfl_xor(s,  off);
      ss += __shfl_xor(ss, off);
    }
    if (k == 0){
      float mu  = s*(1.0f/128.0f);
      float var = fmaxf(ss*(1.0f/128.0f) - mu*mu, 0.f);
      st[i]      = mu;
      st[16 + i] = rsqrtf(var + 1e-5f);
    }
  }
  __syncthreads();
  // phase 3: write row-major bf16, thread (i, c0/8) -> 16B store
  {
    int i = t >> 4, c0 = (t & 15)*8;
    float mu = st[i], inv = st[16 + i];
    bf16 o8[8];
    #pragma unroll
    for (int j=0;j<8;j++){
      int c = c0 + j;
      o8[j] = __float2bfloat16((sm[c*17 + i] - mu)*inv*w[c] + bia[c]);
    }
    *(s8v*)(y + ((long)(b*N_ + nb + i))*C_ + c0) = *(const s8v*)o8;
  }
}

__global__ __launch_bounds__(256)
void ln_tile_kernel(const float* __restrict__ x, const float* __restrict__ w,
                    const float* __restrict__ bia, bf16* __restrict__ y)
{
  __shared__ float sm[128*17];
  __shared__ float st[32];
  ln_tile_body(blockIdx.x, threadIdx.x, x, w, bia, y, sm, st);
}

// ---------------- HEAD: vectorized weight conversion + bias + tokens^T + tiled LN1 --
__global__ __launch_bounds__(256)
void head_kernel(const float* __restrict__ q_w, const float* __restrict__ kv_w,
                 const float* __restrict__ sr_w, const float* __restrict__ proj_w,
                 const float* __restrict__ fc1_w, const float* __restrict__ fc2_w,
                 const float* __restrict__ q_b, const float* __restrict__ kv_b,
                 const float* __restrict__ sr_b, const float* __restrict__ tokens,
                 bf16* __restrict__ out, float* __restrict__ bias_out,
                 float* __restrict__ tokt,
                 const float* __restrict__ x_in, const float* __restrict__ n1w,
                 const float* __restrict__ n1b, bf16* __restrict__ y)
{
  __shared__ float sm[128*17];
  __shared__ float st[32];
  if (blockIdx.x >= 216){
    ln_tile_body(blockIdx.x - 216, threadIdx.x, x_in, n1w, n1b, y, sm, st);
    return;
  }
  int t = blockIdx.x*256 + threadIdx.x;
  if (t < 42304){
    int t0 = t*4;
    const float* src;
    if      (t0 <  16384) src = q_w    + t0;
    else if (t0 <  49152) src = kv_w   + (t0-16384);
    else if (t0 <  65536) src = sr_w   + (t0-49152);
    else if (t0 <  81920) src = proj_w + (t0-65536);
    else                  src = fc1_w  + (t0-81920);
    f4v v = *(const f4v*)src;
    bf16 o4[4];
    #pragma unroll
    for (int j=0;j<4;j++) o4[j] = __float2bfloat16(v[j]);
    *(s4v*)(out + t0) = *(const s4v*)o4;
  } else if (t < 53568){
    int i = (t - 42304)*4;                  // fc2 region, 4 elems within one m
    int m = i / KF2, kp = i % KF2;
    bf16 o4[4];
    #pragma unroll
    for (int j=0;j<4;j++)
      o4[j] = __float2bfloat16((kp+j < HF_) ? fc2_w[m*HF_ + kp + j] : 0.f);
    *(s4v*)(out + 169216 + i) = *(const s4v*)o4;
  } else if (t < 54080){
    int i = t - 53568;
    float bv = (i < 128) ? q_b[i] : (i < 384) ? kv_b[i-128] : sr_b[i-384];
    bias_out[i] = bv;
  } else if (t < 55232){
    int i = t - 54080;                      // (h*9+k)*32 + d
    int hk = i >> 5, d = i & 31;
    int h = hk / 9, k = hk - h*9;
    tokt[i] = tokens[(h*D_ + d)*9 + k];
  }
}

// ---------------- LDS-free MFMA GEMM (batched via blockIdx.z strides) ----------------
template<int KT, int MODE, typename TC, int BM=64, int LDA=KT, int NCH=1>
__global__ __launch_bounds__(256)
void gemm_mfma(const bf16* __restrict__ A, const bf16* __restrict__ B,
               const float* __restrict__ bias, const float* __restrict__ res,
               TC* __restrict__ Cm, int M, int Nn,
               long sA, long sB, long sC, long sR,
               const float* __restrict__ qe, const float* __restrict__ temp,
               bf16* __restrict__ aux0, bf16* __restrict__ aux1)
{
  A  += (long)blockIdx.z * sA;
  B  += (long)blockIdx.z * sB;
  Cm += (long)blockIdx.z * sC;
  if (res) res += (long)blockIdx.z * sR;
  int lane = threadIdx.x & 63, w = threadIdx.x >> 6;
  int m = lane & 15, quad = lane >> 4;
  int n0 = blockIdx.x*64, m0 = blockIdx.y*BM;
  const bf16* ap[NCH];
  #pragma unroll
  for (int cc=0; cc<NCH; cc++){
    int ar = m0 + cc*64 + w*16 + m;
    if (ar >= M) ar = M-1;                      // clamp loads; stores guarded
    ap[cc] = A + (long)ar*LDA + quad*8;
  }
  const bf16* bp = B + (long)(n0 + m)*KT + quad*8;
  s8v a4[KT/32];
  if (MODE==7){
    // in-register LayerNorm of the A rows (stats over 128 via quad-axis shuffles)
    float s=0.f, ssum=0.f;
    #pragma unroll
    for (int i=0;i<KT/32;i++){
      a4[i] = *(const s8v*)(ap[0] + i*32);
      #pragma unroll
      for (int j=0;j<8;j++){
        float v = cvt(((const bf16*)&a4[i])[j]);
        s += v; ssum = fmaf(v,v,ssum);
      }
    }
    s    += __shfl_xor(s,16);    s    += __shfl_xor(s,32);
    ssum += __shfl_xor(ssum,16); ssum += __shfl_xor(ssum,32);
    float mu  = s*(1.0f/128.0f);
    float var = fmaxf(ssum*(1.0f/128.0f) - mu*mu, 0.f);
    float inv = rsqrtf(var + 1e-5f);
    #pragma unroll
    for (int i=0;i<KT/32;i++){
      #pragma unroll
      for (int j=0;j<8;j++){
        int c = i*32 + quad*8 + j;
        float v = cvt(((const bf16*)&a4[i])[j]);
        ((bf16*)&a4[i])[j] = __float2bfloat16((v-mu)*inv*qe[c] + temp[c]);
      }
    }
  }
  f4v acc[NCH][4];
  #pragma unroll
  for (int cc=0; cc<NCH; cc++)
    #pragma unroll
    for (int s=0;s<4;s++) acc[cc][s] = (f4v){0.f,0.f,0.f,0.f};
  __builtin_amdgcn_s_setprio(1);
  #pragma unroll
  for (int k0 = 0; k0 < KT; k0 += 32){
    s8v bf[4];
    #pragma unroll
    for (int s=0;s<4;s++) bf[s] = *(const s8v*)(bp + (long)s*16*KT + k0);
    #pragma unroll
    for (int cc=0; cc<NCH; cc++){
      s8v af = (MODE==7) ? a4[k0/32] : *(const s8v*)(ap[cc] + k0);
      #pragma unroll
      for (int s=0;s<4;s++)
        acc[cc][s] = __builtin_amdgcn_mfma_f32_16x16x32_bf16(af, bf[s], acc[cc][s], 0, 0, 0);
    }
  }
  __builtin_amdgcn_s_setprio(0);
  // ---- specialized epilogues (M is an exact multiple of 64 for modes 6/7) ----
  if ((MODE==6 || MODE==7) && blockIdx.x < 2){
    // normalized section (q for mode 6, k for mode 7); head pair hA,hB
    int hA = blockIdx.x*2, hB = hA+1;
    float spA = 0.f, spB = 0.f;
    if (MODE==6){
      spA = log1pf(expf(temp[hA])) * LOG2E;     // qs carries log2e for exp2-softmax
      spB = log1pf(expf(temp[hB])) * LOG2E;
    }
    #pragma unroll
    for (int cc=0; cc<NCH; cc++){
      #pragma unroll
      for (int r=0;r<4;r++){
        float v4[4];
        #pragma unroll
        for (int s=0;s<4;s++) v4[s] = acc[cc][s][r] + bias[n0 + s*16 + m];
        float ssA = v4[0]*v4[0] + v4[1]*v4[1];
        float ssB = v4[2]*v4[2] + v4[3]*v4[3];
        #pragma unroll
        for (int off=1; off<16; off<<=1){
          ssA += __shfl_xor(ssA, off);
          ssB += __shfl_xor(ssB, off);
        }
        float invA = 1.f/fmaxf(sqrtf(ssA), 1e-12f);
        float invB = 1.f/fmaxf(sqrtf(ssB), 1e-12f);
        int gm = m0 + cc*64 + w*16 + quad*4 + r;
        int b = gm / N_, n = gm % N_;
        #pragma unroll
        for (int s=0;s<4;s++){
          int h = (s<2) ? hA : hB;
          int d = (s&1)*16 + m;
          float v = v4[s] * ((s<2) ? invA : invB);
          if (MODE==6) v = (v + qe[h*D_ + d]) * ((s<2) ? spA : spB);
          aux0[((long)(b*NH_+h)*N_ + n)*D_ + d] = __float2bfloat16(v);
        }
      }
    }
    return;
  }
  if (MODE==7){                                 // v section (bx 2,3) -> v_p planes (bf16)
    int gm0 = m0 + w*16 + quad*4;
    int b = gm0 / N_, nb = gm0 % N_;            // 4 consecutive rows share b (tiles of 4)
    #pragma unroll
    for (int s=0;s<4;s++){
      int h = (blockIdx.x-2)*2 + (s>>1);
      int d = (s&1)*16 + m;
      bf16 p4[4];
      #pragma unroll
      for (int r=0;r<4;r++) p4[r] = __float2bfloat16(acc[0][s][r] + bias[n0 + s*16 + m]);
      *(s4v*)(aux1 + ((long)(b*NH_+h)*D_ + d)*N_ + nb) = *(const s4v*)p4;
    }
    return;
  }
  // ---- generic epilogue ----
  #pragma unroll
  for (int cc=0; cc<NCH; cc++){
    int m0c = m0 + cc*64;
    #pragma unroll
    for (int s=0;s<4;s++){
      int gn = n0 + s*16 + m;
      #pragma unroll
      for (int r=0;r<4;r++){
        int gm = m0c + w*16 + quad*4 + r;
        if (gm >= M) continue;
        float v = acc[cc][s][r];
        if (MODE==1 || MODE==4 || MODE==6) v += bias[gn];
        else                               v += bias[gm];
        if (MODE==6 && gn >= 384) v = gelu_exact(v);
        if (MODE==4 || MODE==5) v += res[(long)gm*Nn + gn];
        stg(&Cm[(long)gm*Nn + gn], v);
      }
    }
  }
}

// ---------------- MFMA pool-attention PARTIAL (fully LDS-free, all-x32, prefetched) -
// r14 PROBE NOTE: this kernel is launched 3x this round (idempotent: Op/Lp are pure
// functions of qs/k_p/v_p). Delta vs r13 = 2*(T_attn_part + dispatch overhead).
__global__ __launch_bounds__(256)
void attn_part_kernel(const bf16* __restrict__ qs_, const bf16* __restrict__ kp_,
                      const bf16* __restrict__ vp_,
                      bf16* __restrict__ Op, float* __restrict__ Lp)
{
  int bh = blockIdx.y;
  int z  = blockIdx.z;
  int lane = threadIdx.x & 63;
  int w    = threadIdx.x >> 6;
  int m    = lane & 15, quad = lane >> 4;
  int base = blockIdx.x*256 + w*16;

  s8v af[4]; bool hasQ[4];
  #pragma unroll
  for (int ch=0; ch<4; ch++){
    int qq = base + ch*64;
    hasQ[ch] = (qq < N_);
    af[ch] = *(const s8v*)(qs_ + ((long)bh*N_ + (hasQ[ch] ? qq : base) + m)*D_ + quad*8);
  }
  const bf16* kpb = kp_ + (long)bh*N_*D_;
  const bf16* vpb = vp_ + (long)bh*D_*N_;
  int kperm = (m & 3) + 8*(m >> 2);            // permuted key row for this lane's A-rows
  const f4v CINIT = {-E8L2, -E8L2, -E8L2, -E8L2};
  f4v o0[4], o1[4];
  float l[4];
  #pragma unroll
  for (int ch=0; ch<4; ch++){
    o0[ch] = (f4v){0.f,0.f,0.f,0.f}; o1[ch] = (f4v){0.f,0.f,0.f,0.f};
    l[ch] = 0.f;
  }

  auto loadKV = [&](s8v* kf, s8v* vf, int t){
    kf[0] = *(const s8v*)(kpb + (long)(t + kperm     )*D_ + quad*8);
    kf[1] = *(const s8v*)(kpb + (long)(t + kperm +  4)*D_ + quad*8);
    kf[2] = *(const s8v*)(kpb + (long)(t + kperm + 32)*D_ + quad*8);
    kf[3] = *(const s8v*)(kpb + (long)(t + kperm + 36)*D_ + quad*8);
    vf[0] = *(const s8v*)(vpb + (long)(m     )*N_ + t      + quad*8);
    vf[1] = *(const s8v*)(vpb + (long)(16 + m)*N_ + t      + quad*8);
    vf[2] = *(const s8v*)(vpb + (long)(m     )*N_ + t + 32 + quad*8);
    vf[3] = *(const s8v*)(vpb + (long)(16 + m)*N_ + t + 32 + quad*8);
  };
  auto compute = [&](const s8v* kf, const s8v* vf){
    __builtin_amdgcn_s_setprio(1);
    #pragma unroll
    for (int ch=0; ch<4; ch++){
      f4v c[4];
      #pragma unroll
      for (int s=0;s<4;s++)
        c[s] = __builtin_amdgcn_mfma_f32_16x16x32_bf16(kf[s], af[ch], CINIT, 0, 0, 0);
      bf16 p8a[8], p8b[8];
      float ls = 0.f;
      #pragma unroll
      for (int r=0;r<4;r++){
        float ea = __builtin_amdgcn_exp2f(c[0][r]);   // keys 8q+r
        float eb = __builtin_amdgcn_exp2f(c[1][r]);   // keys 8q+4+r
        float ec = __builtin_amdgcn_exp2f(c[2][r]);   // +32
        float ed = __builtin_amdgcn_exp2f(c[3][r]);
        ls += (ea+eb) + (ec+ed);
        p8a[r] = __float2bfloat16(ea); p8a[4+r] = __float2bfloat16(eb);
        p8b[r] = __float2bfloat16(ec); p8b[4+r] = __float2bfloat16(ed);
      }
      l[ch] += ls;
      s8v pa = *(const s8v*)p8a, pb = *(const s8v*)p8b;
      o0[ch] = __builtin_amdgcn_mfma_f32_16x16x32_bf16(pa, vf[0], o0[ch], 0, 0, 0);
      o1[ch] = __builtin_amdgcn_mfma_f32_16x16x32_bf16(pa, vf[1], o1[ch], 0, 0, 0);
      o0[ch] = __builtin_amdgcn_mfma_f32_16x16x32_bf16(pb, vf[2], o0[ch], 0, 0, 0);
      o1[ch] = __builtin_amdgcn_mfma_f32_16x16x32_bf16(pb, vf[3], o1[ch], 0, 0, 0);
    }
    __builtin_amdgcn_s_setprio(0);
  };

  int tlo = z*SPLIT, thi = (z==KSP-1) ? N_ : tlo + SPLIT;
  s8v kfA[4], vfA[4], kfB[4], vfB[4];
  int t0 = tlo;
  loadKV(kfA, vfA, t0);
  for (;;){
    if (t0 + 64 < thi) loadKV(kfB, vfB, t0 + 64);
    compute(kfA, vfA);
    t0 += 64;
    if (t0 >= thi) break;
    if (t0 + 64 < thi) loadKV(kfA, vfA, t0 + 64);
    compute(kfB, vfB);
    t0 += 64;
    if (t0 >= thi) break;
  }
  // direct per-lane store: lane(m,quad) reg r holds O[q=quad*4+r][d=m] (o0), [16+m] (o1)
  #pragma unroll
  for (int ch=0; ch<4; ch++){
    if (!hasQ[ch]) continue;
    float lr = l[ch];                          // partial for query m over this quad's keys
    lr += __shfl_xor(lr, 16);
    lr += __shfl_xor(lr, 32);                  // full row sum for query m (replicated)
    long gqBase = (long)bh*N_ + base + ch*64;
    #pragma unroll
    for (int r=0;r<4;r++){
      bf16* op = Op + ((long)z*GQ_ + gqBase + quad*4 + r)*32;
      op[m]      = __float2bfloat16(o0[ch][r]);
      op[16 + m] = __float2bfloat16(o1[ch][r]);
    }
    if (quad == 0) Lp[(long)z*GQ_ + gqBase + m] = lr;
  }
}

// ---------------- combine partials + local 3x3 + learnable tokens -> xo rows --------
__global__ __launch_bounds__(256)
void attn_combine_kernel(const bf16* __restrict__ Op, const float* __restrict__ Lp,
                         const bf16* __restrict__ qs_, const bf16* __restrict__ fused,
                         const float* __restrict__ qe, const float* __restrict__ temp,
                         const float* __restrict__ tokt, const float* __restrict__ tbias,
                         bf16* __restrict__ xo)
{
  int t  = blockIdx.x*256 + threadIdx.x;       // 8 threads per query
  int gq = t >> 3;                             // bh*N + n
  int l8 = t & 7;
  int d0 = l8*4;
  int n = gq % N_; int bh = gq / N_; int h = bh & 3; int b = bh >> 2;
  float out[4] = {0.f,0.f,0.f,0.f};
  // partial-O accumulate (8B per z); Lp: one per lane (KSP == 8-lane group size)
  #pragma unroll
  for (int z=0; z<KSP; z++){
    s4v o4 = *(const s4v*)(Op + ((long)z*GQ_ + gq)*32 + d0);
    #pragma unroll
    for (int j=0;j<4;j++) out[j] += cvt(((const bf16*)&o4)[j]);
  }
  float L = Lp[(long)l8*GQ_ + gq];
  #pragma unroll
  for (int off=1; off<8; off<<=1) L += __shfl_xor(L, off);
  // q chunk (undo the log2e scale baked into qs)
  float q[4];
  {
    s4v q4 = *(const s4v*)(qs_ + (long)gq*D_ + d0);
    #pragma unroll
    for (int j=0;j<4;j++) q[j] = cvt(((const bf16*)&q4)[j]) * 0.6931471805599453f;
  }
  int hy = n / W_, wx = n % W_;
  const bf16* kvb = fused + (long)b*N_*FW + 128 + h*D_ + d0;   // key cols (this lane's d's)
  float sl[9];
  #pragma unroll
  for (int k=0;k<9;k++){
    int di = k/3-1, dj = k%3-1;
    int yy = hy+di, xx = wx+dj;
    bool ok = (yy>=0 && yy<H_ && xx>=0 && xx<W_);              // uniform within group
    float dot = 0.f, ss = 0.f;
    if (ok){
      s4v k4 = *(const s4v*)(kvb + (long)(yy*W_+xx)*FW);
      #pragma unroll
      for (int j=0;j<4;j++){
        float kk = cvt(((const bf16*)&k4)[j]);
        dot = fmaf(q[j], kk, dot);
        ss  = fmaf(kk, kk, ss);
      }
    }
    #pragma unroll
    for (int off=1; off<8; off<<=1){
      dot += __shfl_xor(dot, off);
      ss  += __shfl_xor(ss,  off);
    }
    sl[k] = ok ? dot / fmaxf(sqrtf(ss), 1e-12f) : 0.f;         // OOB: exactly 0
  }
  #pragma unroll
  for (int k=0;k<9;k++) L += __expf(sl[k] - 8.f);
  float invL = 1.f/L;
  #pragma unroll
  for (int j=0;j<4;j++) out[j] *= invL;
  float sp = log1pf(expf(temp[h]));
  float invsp = 1.f/sp;
  float qn[4];
  #pragma unroll
  for (int j=0;j<4;j++) qn[j] = q[j]*invsp - qe[h*D_ + d0 + j];
  const float* tk = tokt + (long)h*9*D_ + d0;
  #pragma unroll
  for (int k=0;k<9;k++){
    f4v tv = *(const f4v*)(tk + k*D_);
    float tok = qn[0]*tv[0] + qn[1]*tv[1] + qn[2]*tv[2] + qn[3]*tv[3];
    #pragma unroll
    for (int off=1; off<8; off<<=1) tok += __shfl_xor(tok, off);
    float wl = tok + tbias[h*9+k] + __expf(sl[k] - 8.f)*invL;
    int di = k/3-1, dj = k%3-1;
    int yy = hy+di, xx = wx+dj;
    if (yy>=0 && yy<H_ && xx>=0 && xx<W_){                     // OOB v_l -> contributes 0
      s4v v4 = *(const s4v*)(kvb + (long)(yy*W_+xx)*FW + 128);
      #pragma unroll
      for (int j=0;j<4;j++) out[j] = fmaf(wl, cvt(((const bf16*)&v4)[j]), out[j]);
    }
  }
  bf16 o4[4];
  #pragma unroll
  for (int j=0;j<4;j++) o4[j] = __float2bfloat16(out[j]);
  *(s4v*)(xo + ((long)(b*N_ + n))*C_ + h*D_ + d0) = *(const s4v*)o4;
}

// ---------------- depthwise 3x3 + bias + gelu, gated -> g ROWS (n, 352) -------------
__global__ __launch_bounds__(256)
void dwconv_kernel(const bf16* __restrict__ f1, const float* __restrict__ dww,
                   const float* __restrict__ dwb, bf16* __restrict__ g)
{
  __shared__ bf16 sg[32*72];                   // 32 c x 64 n, stride 72 (4-way on write)
  int bx = blockIdx.x;                         // ((b*11 + cg)*49 + ntile)
  int ntile = bx % 49;
  int cg    = (bx / 49) % 11;
  int b     = bx / (49*11);
  int t = threadIdx.x;
  f1 += (long)b*2*HF_*N_;
  {
    int c_local = t & 31, chun = t >> 5;
    int c = cg*32 + c_local;
    int n0 = ntile*64 + chun*8;
    int y = n0 / W_, x0 = n0 % W_;             // chunks never cross rows (8 | 56)
    bf16 o8[8];
    if (c < HF_){
      const bf16* ap = f1 + (long)c*N_;
      float acc[8];
      #pragma unroll
      for (int j=0;j<8;j++) acc[j] = dwb[c];
      #pragma unroll
      for (int dy=-1; dy<=1; dy++){
        int yy = y + dy;
        if (yy < 0 || yy >= H_) continue;
        int base = yy*W_ + x0;
        s8v mid = *(const s8v*)(ap + base);    // 16B aligned (112|yy*W_*2, 16|x0*2)
        float wnd[10];
        wnd[0] = (x0 > 0)      ? cvt(ap[base-1]) : 0.f;
        #pragma unroll
        for (int j=0;j<8;j++) wnd[1+j] = cvt(((const bf16*)&mid)[j]);
        wnd[9] = (x0 + 8 < W_) ? cvt(ap[base+8]) : 0.f;
        float k0 = dww[c*9 + (dy+1)*3    ];
        float k1 = dww[c*9 + (dy+1)*3 + 1];
        float k2 = dww[c*9 + (dy+1)*3 + 2];
        #pragma unroll
        for (int j=0;j<8;j++)
          acc[j] = fmaf(k0, wnd[j], fmaf(k1, wnd[j+1], fmaf(k2, wnd[j+2], acc[j])));
      }
      s8v g8 = *(const s8v*)(f1 + (long)(HF_+c)*N_ + n0);
      #pragma unroll
      for (int j=0;j<8;j++)
        o8[j] = __float2bfloat16(gelu_exact(acc[j]) * cvt(((const bf16*)&g8)[j]));
    } else {
      #pragma unroll
      for (int j=0;j<8;j++) o8[j] = __float2bfloat16(0.f);
    }
    *(s8v*)(&sg[c_local*72 + chun*8]) = *(const s8v*)o8;
  }
  __syncthreads();
  {
    int n_local = t >> 2, c0 = (t & 3)*8;
    bf16 o8[8];
    #pragma unroll
    for (int j=0;j<8;j++) o8[j] = sg[(c0+j)*72 + n_local];
    *(s8v*)(g + (long)b*N_*KF2 + (long)(ntile*64 + n_local)*KF2 + cg*32 + c0)
        = *(const s8v*)o8;
  }
}

// ---------------- launcher ----------------
extern "C" void kernel_launch(void* const* d_in, const int* in_sizes, int n_in,
                              void* d_out, int out_size, void* d_ws, size_t ws_size,
                              hipStream_t stream)
{
  (void)in_sizes; (void)n_in; (void)out_size; (void)ws_size;
  const float* x_in      = (const float*)d_in[0];
  const float* norm1_w   = (const float*)d_in[1];
  const float* norm1_b   = (const float*)d_in[2];
  const float* q_w       = (const float*)d_in[3];
  const float* q_b       = (const float*)d_in[4];
  const float* kv_w      = (const float*)d_in[5];
  const float* kv_b      = (const float*)d_in[6];
  const float* temp      = (const float*)d_in[7];
  const float* qe        = (const float*)d_in[8];
  const float* tokens    = (const float*)d_in[9];
  const float* tbias     = (const float*)d_in[10];
  const float* sr_w      = (const float*)d_in[11];
  const float* sr_b      = (const float*)d_in[12];
  const float* pln_w     = (const float*)d_in[13];
  const float* pln_b     = (const float*)d_in[14];
  const float* proj_w    = (const float*)d_in[15];
  const float* proj_b    = (const float*)d_in[16];
  const float* norm2_w   = (const float*)d_in[17];
  const float* norm2_b   = (const float*)d_in[18];
  const float* fc1_w     = (const float*)d_in[19];
  const float* fc1_b     = (const float*)d_in[20];
  const float* dw_w      = (const float*)d_in[21];
  const float* dw_b      = (const float*)d_in[22];
  const float* fc2_w     = (const float*)d_in[23];
  const float* fc2_b     = (const float*)d_in[24];

  char* w8 = (char*)d_ws;
  bf16*  fused   = (bf16*)(w8 + 0);
  float* x2      = (float*)(w8 + 0);
  bf16*  y2      = (bf16*)(w8 + 3211264);
  bf16*  f1b     = (bf16*)(w8 + 4816896);
  bf16*  qs      = (bf16*)(w8 + 6422528);
  bf16*  k_p     = (bf16*)(w8 + 9633792);
  bf16*  v_p     = (bf16*)(w8 + 11239424);
  bf16*  Opart   = (bf16*)(w8 + 13045056);
  bf16*  g_rows  = (bf16*)(w8 + 32312640);
  bf16*  wbase   = (bf16*)(w8 + 36728128);
  float* fbias   = (float*)(w8 + 37156672);
  float* tokt    = (float*)(w8 + 37158720);
  bf16*  y       = f1b;                         // LN1 output rows (dead before f1b use)
  bf16*  xo      = (bf16*)d_out;
  float* Lpart   = (float*)((char*)d_out + 1605632);
  bf16*  proj_wb = wbase + 65536;
  bf16*  fc1_wb  = wbase + 81920;
  bf16*  fc2_wb  = wbase + 169216;

  // 0. weights -> bf16 (vectorized) + bias + tokens^T + tiled LN1 (216+392 blocks)
  head_kernel<<<216 + NTILE, 256, 0, stream>>>(
      q_w, kv_w, sr_w, proj_w, fc1_w, fc2_w, q_b, kv_b, sr_b, tokens,
      wbase, fbias, tokt, x_in, norm1_w, norm1_b, y);
  // 2. fused = y @ [q_w; kv_w; sr_w]^T + bias
  gemm_mfma<128, 6, bf16, 128, 128, 2><<<dim3(8,49), 256, 0, stream>>>(
      y, wbase, fbias, nullptr, fused, ROWS_, FW, 0,0,0,0, qe, temp, qs, nullptr);
  // 4. kvp = LN_pln(fused sr cols) @ kv_w^T + kv_b
  gemm_mfma<128, 7, bf16, 64, FW><<<dim3(4,98), 256, 0, stream>>>(
      fused + 384, wbase + 16384, kv_b, nullptr, (bf16*)nullptr, ROWS_, 256, 0,0,0,0,
      pln_w, pln_b, k_p, v_p);
  // 5. pool-attention partials.
  // ===== r14 MEASUREMENT: launched 3x (idempotent). dur delta vs r13 = 2*(T+OH) =====
  attn_part_kernel<<<dim3(13,8,KSP), 256, 0, stream>>>(qs, k_p, v_p, Opart, Lpart);
  attn_part_kernel<<<dim3(13,8,KSP), 256, 0, stream>>>(qs, k_p, v_p, Opart, Lpart);
  attn_part_kernel<<<dim3(13,8,KSP), 256, 0, stream>>>(qs, k_p, v_p, Opart, Lpart);
  // 6. combine + local 3x3 + tokens -> xo
  attn_combine_kernel<<<GQ_*8/256, 256, 0, stream>>>(Opart, Lpart, qs, fused,
                                                     qe, temp, tokt, tbias, xo);
  // 7. x2 = x_in + (xo @ proj_w^T + proj_b)
  gemm_mfma<128, 4, float, 16><<<dim3(2,392), 64, 0, stream>>>(
      xo, proj_wb, proj_b, x_in, x2, ROWS_, 128, 0,0,0,0, nullptr, nullptr, nullptr, nullptr);
  // 8. y2 = LN2(x2)
  ln_tile_kernel<<<NTILE, 256, 0, stream>>>(x2, norm2_w, norm2_b, y2);
  // 9. MLP
  gemm_mfma<128, 3, bf16, 128, 128, 2><<<dim3(49,6,B_), 256, 0, stream>>>(
      fc1_wb, y2, fc1_b, nullptr, f1b, 2*HF_, N_,
      0, (long)N_*C_, (long)2*HF_*N_, 0, nullptr, nullptr, nullptr, nullptr);
  dwconv_kernel<<<B_*11*49, 256, 0, stream>>>(f1b, dw_w, dw_b, g_rows);
  gemm_mfma<KF2, 5, float, 16><<<dim3(49,8,B_), 64, 0, stream>>>(
      fc2_wb, g_rows, fc2_b, x2, (float*)d_out, C_, N_,
      0, (long)N_*KF2, (long)C_*N_, (long)C_*N_, nullptr, nullptr, nullptr, nullptr);
}

// Round 15
// 226.396 us; speedup vs baseline: 1.2108x; 1.2108x over previous
//
#include <hip/hip_runtime.h>
#include <hip/hip_bf16.h>

typedef __hip_bfloat16 bf16;
typedef short s8v __attribute__((ext_vector_type(8)));   // 8 bf16 = 4 VGPR MFMA frag
typedef short s4v __attribute__((ext_vector_type(4)));   // 4 bf16 = 8B packed store
typedef float f4v __attribute__((ext_vector_type(4)));   // 4 fp32 MFMA acc

#define DEVI __device__ __forceinline__

DEVI float cvt(float x){ return x; }
DEVI float cvt(bf16 x){ return __bfloat162float(x); }

DEVI void stg(float* p, float v){ *p = v; }
DEVI void stg(bf16* p, float v){ *p = __float2bfloat16(v); }

DEVI float gelu_exact(float x){
  return 0.5f*x*(1.0f + erff(x*0.70710678118654752440f));
}

// problem constants
constexpr int B_ = 2, C_ = 128, H_ = 56, W_ = 56, N_ = 3136, NH_ = 4, D_ = 32, HF_ = 341;
constexpr int ROWS_ = B_*N_;             // 6272
constexpr int KF2 = 352;                 // fc2 K padded 341 -> 352 (11*32)
constexpr int GQ_ = NH_*B_*N_;           // 25088 (bh*N + n)
constexpr int FW = 512;                  // fused qkv+sr width (q 0..128 | kv 128..384 | sr 384..512)
constexpr int KSP = 8;                   // attention key splits
constexpr int SPLIT = 384;               // keys per split (6 tiles; last split gets 448)
constexpr int NTILE = 392;               // LN tiles (6272/16)
constexpr float LOG2E = 1.4426950408889634f;
constexpr float E8L2  = 11.541560327111707f;   // 8*log2(e); exp(s-8) = exp2(s*log2e - E8L2)

// ---------------- tiled plane->row LayerNorm (16 rows x 128 ch per block) ----------
DEVI void ln_tile_body(int tile, int t, const float* __restrict__ x,
                       const float* __restrict__ w, const float* __restrict__ bia,
                       bf16* __restrict__ y, float* sm /*128*17*/, float* st /*32*/)
{
  int b = tile / 196, nb = (tile % 196) * 16;
  // phase 1: load 16 rows x 128 ch, thread (c,half) -> 8 consecutive n (two float4)
  {
    int c = t >> 1, half = t & 1;
    const float* xp = x + ((long)b*C_ + c)*N_ + nb + half*8;
    f4v v0 = *(const f4v*)xp;
    f4v v1 = *(const f4v*)(xp + 4);
    #pragma unroll
    for (int j=0;j<4;j++){
      sm[c*17 + half*8 + j    ] = v0[j];
      sm[c*17 + half*8 + 4 + j] = v1[j];
    }
  }
  __syncthreads();
  // phase 2: row stats; 16 threads per row, each sums 8 channels, xor-reduce low 4 bits
  {
    int i = t >> 4, k = t & 15;
    float s = 0.f, ss = 0.f;
    #pragma unroll
    for (int u=0;u<8;u++){
      float v = sm[(k + u*16)*17 + i];
      s += v; ss = fmaf(v,v,ss);
    }
    #pragma unroll
    for (int off=1; off<16; off<<=1){
      s  += __shfl_xor(s,  off);
      ss += __shfl_xor(ss, off);
    }
    if (k == 0){
      float mu  = s*(1.0f/128.0f);
      float var = fmaxf(ss*(1.0f/128.0f) - mu*mu, 0.f);
      st[i]      = mu;
      st[16 + i] = rsqrtf(var + 1e-5f);
    }
  }
  __syncthreads();
  // phase 3: write row-major bf16, thread (i, c0/8) -> 16B store
  {
    int i = t >> 4, c0 = (t & 15)*8;
    float mu = st[i], inv = st[16 + i];
    bf16 o8[8];
    #pragma unroll
    for (int j=0;j<8;j++){
      int c = c0 + j;
      o8[j] = __float2bfloat16((sm[c*17 + i] - mu)*inv*w[c] + bia[c]);
    }
    *(s8v*)(y + ((long)(b*N_ + nb + i))*C_ + c0) = *(const s8v*)o8;
  }
}

__global__ __launch_bounds__(256)
void ln_tile_kernel(const float* __restrict__ x, const float* __restrict__ w,
                    const float* __restrict__ bia, bf16* __restrict__ y)
{
  __shared__ float sm[128*17];
  __shared__ float st[32];
  ln_tile_body(blockIdx.x, threadIdx.x, x, w, bia, y, sm, st);
}

// ---------------- HEAD: vectorized weight conversion + bias + tokens^T + tiled LN1 --
__global__ __launch_bounds__(256)
void head_kernel(const float* __restrict__ q_w, const float* __restrict__ kv_w,
                 const float* __restrict__ sr_w, const float* __restrict__ proj_w,
                 const float* __restrict__ fc1_w, const float* __restrict__ fc2_w,
                 const float* __restrict__ q_b, const float* __restrict__ kv_b,
                 const float* __restrict__ sr_b, const float* __restrict__ tokens,
                 bf16* __restrict__ out, float* __restrict__ bias_out,
                 float* __restrict__ tokt,
                 const float* __restrict__ x_in, const float* __restrict__ n1w,
                 const float* __restrict__ n1b, bf16* __restrict__ y)
{
  __shared__ float sm[128*17];
  __shared__ float st[32];
  if (blockIdx.x >= 216){
    ln_tile_body(blockIdx.x - 216, threadIdx.x, x_in, n1w, n1b, y, sm, st);
    return;
  }
  int t = blockIdx.x*256 + threadIdx.x;
  if (t < 42304){
    int t0 = t*4;
    const float* src;
    if      (t0 <  16384) src = q_w    + t0;
    else if (t0 <  49152) src = kv_w   + (t0-16384);
    else if (t0 <  65536) src = sr_w   + (t0-49152);
    else if (t0 <  81920) src = proj_w + (t0-65536);
    else                  src = fc1_w  + (t0-81920);
    f4v v = *(const f4v*)src;
    bf16 o4[4];
    #pragma unroll
    for (int j=0;j<4;j++) o4[j] = __float2bfloat16(v[j]);
    *(s4v*)(out + t0) = *(const s4v*)o4;
  } else if (t < 53568){
    int i = (t - 42304)*4;                  // fc2 region, 4 elems within one m
    int m = i / KF2, kp = i % KF2;
    bf16 o4[4];
    #pragma unroll
    for (int j=0;j<4;j++)
      o4[j] = __float2bfloat16((kp+j < HF_) ? fc2_w[m*HF_ + kp + j] : 0.f);
    *(s4v*)(out + 169216 + i) = *(const s4v*)o4;
  } else if (t < 54080){
    int i = t - 53568;
    float bv = (i < 128) ? q_b[i] : (i < 384) ? kv_b[i-128] : sr_b[i-384];
    bias_out[i] = bv;
  } else if (t < 55232){
    int i = t - 54080;                      // (h*9+k)*32 + d
    int hk = i >> 5, d = i & 31;
    int h = hk / 9, k = hk - h*9;
    tokt[i] = tokens[(h*D_ + d)*9 + k];
  }
}

// ---------------- LDS-free MFMA GEMM (batched via blockIdx.z strides) ----------------
template<int KT, int MODE, typename TC, int BM=64, int LDA=KT, int NCH=1>
__global__ __launch_bounds__(256)
void gemm_mfma(const bf16* __restrict__ A, const bf16* __restrict__ B,
               const float* __restrict__ bias, const float* __restrict__ res,
               TC* __restrict__ Cm, int M, int Nn,
               long sA, long sB, long sC, long sR,
               const float* __restrict__ qe, const float* __restrict__ temp,
               bf16* __restrict__ aux0, bf16* __restrict__ aux1)
{
  A  += (long)blockIdx.z * sA;
  B  += (long)blockIdx.z * sB;
  Cm += (long)blockIdx.z * sC;
  if (res) res += (long)blockIdx.z * sR;
  int lane = threadIdx.x & 63, w = threadIdx.x >> 6;
  int m = lane & 15, quad = lane >> 4;
  int n0 = blockIdx.x*64, m0 = blockIdx.y*BM;
  const bf16* ap[NCH];
  #pragma unroll
  for (int cc=0; cc<NCH; cc++){
    int ar = m0 + cc*64 + w*16 + m;
    if (ar >= M) ar = M-1;                      // clamp loads; stores guarded
    ap[cc] = A + (long)ar*LDA + quad*8;
  }
  const bf16* bp = B + (long)(n0 + m)*KT + quad*8;
  s8v a4[KT/32];
  if (MODE==7){
    // in-register LayerNorm of the A rows (stats over 128 via quad-axis shuffles)
    float s=0.f, ssum=0.f;
    #pragma unroll
    for (int i=0;i<KT/32;i++){
      a4[i] = *(const s8v*)(ap[0] + i*32);
      #pragma unroll
      for (int j=0;j<8;j++){
        float v = cvt(((const bf16*)&a4[i])[j]);
        s += v; ssum = fmaf(v,v,ssum);
      }
    }
    s    += __shfl_xor(s,16);    s    += __shfl_xor(s,32);
    ssum += __shfl_xor(ssum,16); ssum += __shfl_xor(ssum,32);
    float mu  = s*(1.0f/128.0f);
    float var = fmaxf(ssum*(1.0f/128.0f) - mu*mu, 0.f);
    float inv = rsqrtf(var + 1e-5f);
    #pragma unroll
    for (int i=0;i<KT/32;i++){
      #pragma unroll
      for (int j=0;j<8;j++){
        int c = i*32 + quad*8 + j;
        float v = cvt(((const bf16*)&a4[i])[j]);
        ((bf16*)&a4[i])[j] = __float2bfloat16((v-mu)*inv*qe[c] + temp[c]);
      }
    }
  }
  f4v acc[NCH][4];
  #pragma unroll
  for (int cc=0; cc<NCH; cc++)
    #pragma unroll
    for (int s=0;s<4;s++) acc[cc][s] = (f4v){0.f,0.f,0.f,0.f};
  __builtin_amdgcn_s_setprio(1);
  #pragma unroll
  for (int k0 = 0; k0 < KT; k0 += 32){
    s8v bf[4];
    #pragma unroll
    for (int s=0;s<4;s++) bf[s] = *(const s8v*)(bp + (long)s*16*KT + k0);
    #pragma unroll
    for (int cc=0; cc<NCH; cc++){
      s8v af = (MODE==7) ? a4[k0/32] : *(const s8v*)(ap[cc] + k0);
      #pragma unroll
      for (int s=0;s<4;s++)
        acc[cc][s] = __builtin_amdgcn_mfma_f32_16x16x32_bf16(af, bf[s], acc[cc][s], 0, 0, 0);
    }
  }
  __builtin_amdgcn_s_setprio(0);
  // ---- specialized epilogues (M is an exact multiple of 64 for modes 6/7) ----
  if ((MODE==6 || MODE==7) && blockIdx.x < 2){
    // normalized section (q for mode 6, k for mode 7); head pair hA,hB
    int hA = blockIdx.x*2, hB = hA+1;
    float spA = 0.f, spB = 0.f;
    if (MODE==6){
      spA = log1pf(expf(temp[hA])) * LOG2E;     // qs carries log2e for exp2-softmax
      spB = log1pf(expf(temp[hB])) * LOG2E;
    }
    #pragma unroll
    for (int cc=0; cc<NCH; cc++){
      #pragma unroll
      for (int r=0;r<4;r++){
        float v4[4];
        #pragma unroll
        for (int s=0;s<4;s++) v4[s] = acc[cc][s][r] + bias[n0 + s*16 + m];
        float ssA = v4[0]*v4[0] + v4[1]*v4[1];
        float ssB = v4[2]*v4[2] + v4[3]*v4[3];
        #pragma unroll
        for (int off=1; off<16; off<<=1){
          ssA += __shfl_xor(ssA, off);
          ssB += __shfl_xor(ssB, off);
        }
        float invA = 1.f/fmaxf(sqrtf(ssA), 1e-12f);
        float invB = 1.f/fmaxf(sqrtf(ssB), 1e-12f);
        int gm = m0 + cc*64 + w*16 + quad*4 + r;
        int b = gm / N_, n = gm % N_;
        #pragma unroll
        for (int s=0;s<4;s++){
          int h = (s<2) ? hA : hB;
          int d = (s&1)*16 + m;
          float v = v4[s] * ((s<2) ? invA : invB);
          if (MODE==6) v = (v + qe[h*D_ + d]) * ((s<2) ? spA : spB);
          aux0[((long)(b*NH_+h)*N_ + n)*D_ + d] = __float2bfloat16(v);
        }
      }
    }
    return;
  }
  if (MODE==7){                                 // v section (bx 2,3) -> v_p planes (bf16)
    int gm0 = m0 + w*16 + quad*4;
    int b = gm0 / N_, nb = gm0 % N_;            // 4 consecutive rows share b (tiles of 4)
    #pragma unroll
    for (int s=0;s<4;s++){
      int h = (blockIdx.x-2)*2 + (s>>1);
      int d = (s&1)*16 + m;
      bf16 p4[4];
      #pragma unroll
      for (int r=0;r<4;r++) p4[r] = __float2bfloat16(acc[0][s][r] + bias[n0 + s*16 + m]);
      *(s4v*)(aux1 + ((long)(b*NH_+h)*D_ + d)*N_ + nb) = *(const s4v*)p4;
    }
    return;
  }
  // ---- generic epilogue ----
  #pragma unroll
  for (int cc=0; cc<NCH; cc++){
    int m0c = m0 + cc*64;
    #pragma unroll
    for (int s=0;s<4;s++){
      int gn = n0 + s*16 + m;
      #pragma unroll
      for (int r=0;r<4;r++){
        int gm = m0c + w*16 + quad*4 + r;
        if (gm >= M) continue;
        float v = acc[cc][s][r];
        if (MODE==1 || MODE==4 || MODE==6) v += bias[gn];
        else                               v += bias[gm];
        if (MODE==6 && gn >= 384) v = gelu_exact(v);
        if (MODE==4 || MODE==5) v += res[(long)gm*Nn + gn];
        stg(&Cm[(long)gm*Nn + gn], v);
      }
    }
  }
}

// ---------------- MFMA pool-attention PARTIAL (fully LDS-free, all-x32, prefetched) -
// r15: PROBE MEASURED 26us in-graph at 3.25 blocks/CU with VALU ~46% busy -- the
// QK->exp->pack->PV chains lack overlap. Chains/wave 4 -> 2, q-grid 13 -> 25:
// grid (25,8,8) = 1600 blocks = 6.25/CU = 25 waves/CU (2x overlap). K/V L2 traffic
// doubles (21->42MB, ~2us at L2 agg BW -- cheap). VGPR drops ~72 -> ~56.
__global__ __launch_bounds__(256)
void attn_part_kernel(const bf16* __restrict__ qs_, const bf16* __restrict__ kp_,
                      const bf16* __restrict__ vp_,
                      bf16* __restrict__ Op, float* __restrict__ Lp)
{
  int bh = blockIdx.y;
  int z  = blockIdx.z;
  int lane = threadIdx.x & 63;
  int w    = threadIdx.x >> 6;
  int m    = lane & 15, quad = lane >> 4;
  int base = blockIdx.x*128 + w*16;

  s8v af[2]; bool hasQ[2];
  #pragma unroll
  for (int ch=0; ch<2; ch++){
    int qq = base + ch*64;
    hasQ[ch] = (qq < N_);
    af[ch] = *(const s8v*)(qs_ + ((long)bh*N_ + (hasQ[ch] ? qq : base) + m)*D_ + quad*8);
  }
  const bf16* kpb = kp_ + (long)bh*N_*D_;
  const bf16* vpb = vp_ + (long)bh*D_*N_;
  int kperm = (m & 3) + 8*(m >> 2);            // permuted key row for this lane's A-rows
  const f4v CINIT = {-E8L2, -E8L2, -E8L2, -E8L2};
  f4v o0[2], o1[2];
  float l[2];
  #pragma unroll
  for (int ch=0; ch<2; ch++){
    o0[ch] = (f4v){0.f,0.f,0.f,0.f}; o1[ch] = (f4v){0.f,0.f,0.f,0.f};
    l[ch] = 0.f;
  }

  auto loadKV = [&](s8v* kf, s8v* vf, int t){
    kf[0] = *(const s8v*)(kpb + (long)(t + kperm     )*D_ + quad*8);
    kf[1] = *(const s8v*)(kpb + (long)(t + kperm +  4)*D_ + quad*8);
    kf[2] = *(const s8v*)(kpb + (long)(t + kperm + 32)*D_ + quad*8);
    kf[3] = *(const s8v*)(kpb + (long)(t + kperm + 36)*D_ + quad*8);
    vf[0] = *(const s8v*)(vpb + (long)(m     )*N_ + t      + quad*8);
    vf[1] = *(const s8v*)(vpb + (long)(16 + m)*N_ + t      + quad*8);
    vf[2] = *(const s8v*)(vpb + (long)(m     )*N_ + t + 32 + quad*8);
    vf[3] = *(const s8v*)(vpb + (long)(16 + m)*N_ + t + 32 + quad*8);
  };
  auto compute = [&](const s8v* kf, const s8v* vf){
    __builtin_amdgcn_s_setprio(1);
    #pragma unroll
    for (int ch=0; ch<2; ch++){
      f4v c[4];
      #pragma unroll
      for (int s=0;s<4;s++)
        c[s] = __builtin_amdgcn_mfma_f32_16x16x32_bf16(kf[s], af[ch], CINIT, 0, 0, 0);
      bf16 p8a[8], p8b[8];
      float ls = 0.f;
      #pragma unroll
      for (int r=0;r<4;r++){
        float ea = __builtin_amdgcn_exp2f(c[0][r]);   // keys 8q+r
        float eb = __builtin_amdgcn_exp2f(c[1][r]);   // keys 8q+4+r
        float ec = __builtin_amdgcn_exp2f(c[2][r]);   // +32
        float ed = __builtin_amdgcn_exp2f(c[3][r]);
        ls += (ea+eb) + (ec+ed);
        p8a[r] = __float2bfloat16(ea); p8a[4+r] = __float2bfloat16(eb);
        p8b[r] = __float2bfloat16(ec); p8b[4+r] = __float2bfloat16(ed);
      }
      l[ch] += ls;
      s8v pa = *(const s8v*)p8a, pb = *(const s8v*)p8b;
      o0[ch] = __builtin_amdgcn_mfma_f32_16x16x32_bf16(pa, vf[0], o0[ch], 0, 0, 0);
      o1[ch] = __builtin_amdgcn_mfma_f32_16x16x32_bf16(pa, vf[1], o1[ch], 0, 0, 0);
      o0[ch] = __builtin_amdgcn_mfma_f32_16x16x32_bf16(pb, vf[2], o0[ch], 0, 0, 0);
      o1[ch] = __builtin_amdgcn_mfma_f32_16x16x32_bf16(pb, vf[3], o1[ch], 0, 0, 0);
    }
    __builtin_amdgcn_s_setprio(0);
  };

  int tlo = z*SPLIT, thi = (z==KSP-1) ? N_ : tlo + SPLIT;
  s8v kfA[4], vfA[4], kfB[4], vfB[4];
  int t0 = tlo;
  loadKV(kfA, vfA, t0);
  for (;;){
    if (t0 + 64 < thi) loadKV(kfB, vfB, t0 + 64);
    compute(kfA, vfA);
    t0 += 64;
    if (t0 >= thi) break;
    if (t0 + 64 < thi) loadKV(kfA, vfA, t0 + 64);
    compute(kfB, vfB);
    t0 += 64;
    if (t0 >= thi) break;
  }
  // direct per-lane store: lane(m,quad) reg r holds O[q=quad*4+r][d=m] (o0), [16+m] (o1)
  #pragma unroll
  for (int ch=0; ch<2; ch++){
    if (!hasQ[ch]) continue;
    float lr = l[ch];                          // partial for query m over this quad's keys
    lr += __shfl_xor(lr, 16);
    lr += __shfl_xor(lr, 32);                  // full row sum for query m (replicated)
    long gqBase = (long)bh*N_ + base + ch*64;
    #pragma unroll
    for (int r=0;r<4;r++){
      bf16* op = Op + ((long)z*GQ_ + gqBase + quad*4 + r)*32;
      op[m]      = __float2bfloat16(o0[ch][r]);
      op[16 + m] = __float2bfloat16(o1[ch][r]);
    }
    if (quad == 0) Lp[(long)z*GQ_ + gqBase + m] = lr;
  }
}

// ---------------- combine partials + local 3x3 + learnable tokens -> xo rows --------
__global__ __launch_bounds__(256)
void attn_combine_kernel(const bf16* __restrict__ Op, const float* __restrict__ Lp,
                         const bf16* __restrict__ qs_, const bf16* __restrict__ fused,
                         const float* __restrict__ qe, const float* __restrict__ temp,
                         const float* __restrict__ tokt, const float* __restrict__ tbias,
                         bf16* __restrict__ xo)
{
  int t  = blockIdx.x*256 + threadIdx.x;       // 8 threads per query
  int gq = t >> 3;                             // bh*N + n
  int l8 = t & 7;
  int d0 = l8*4;
  int n = gq % N_; int bh = gq / N_; int h = bh & 3; int b = bh >> 2;
  float out[4] = {0.f,0.f,0.f,0.f};
  // partial-O accumulate (8B per z); Lp: one per lane (KSP == 8-lane group size)
  #pragma unroll
  for (int z=0; z<KSP; z++){
    s4v o4 = *(const s4v*)(Op + ((long)z*GQ_ + gq)*32 + d0);
    #pragma unroll
    for (int j=0;j<4;j++) out[j] += cvt(((const bf16*)&o4)[j]);
  }
  float L = Lp[(long)l8*GQ_ + gq];
  #pragma unroll
  for (int off=1; off<8; off<<=1) L += __shfl_xor(L, off);
  // q chunk (undo the log2e scale baked into qs)
  float q[4];
  {
    s4v q4 = *(const s4v*)(qs_ + (long)gq*D_ + d0);
    #pragma unroll
    for (int j=0;j<4;j++) q[j] = cvt(((const bf16*)&q4)[j]) * 0.6931471805599453f;
  }
  int hy = n / W_, wx = n % W_;
  const bf16* kvb = fused + (long)b*N_*FW + 128 + h*D_ + d0;   // key cols (this lane's d's)
  float sl[9];
  #pragma unroll
  for (int k=0;k<9;k++){
    int di = k/3-1, dj = k%3-1;
    int yy = hy+di, xx = wx+dj;
    bool ok = (yy>=0 && yy<H_ && xx>=0 && xx<W_);              // uniform within group
    float dot = 0.f, ss = 0.f;
    if (ok){
      s4v k4 = *(const s4v*)(kvb + (long)(yy*W_+xx)*FW);
      #pragma unroll
      for (int j=0;j<4;j++){
        float kk = cvt(((const bf16*)&k4)[j]);
        dot = fmaf(q[j], kk, dot);
        ss  = fmaf(kk, kk, ss);
      }
    }
    #pragma unroll
    for (int off=1; off<8; off<<=1){
      dot += __shfl_xor(dot, off);
      ss  += __shfl_xor(ss,  off);
    }
    sl[k] = ok ? dot / fmaxf(sqrtf(ss), 1e-12f) : 0.f;         // OOB: exactly 0
  }
  #pragma unroll
  for (int k=0;k<9;k++) L += __expf(sl[k] - 8.f);
  float invL = 1.f/L;
  #pragma unroll
  for (int j=0;j<4;j++) out[j] *= invL;
  float sp = log1pf(expf(temp[h]));
  float invsp = 1.f/sp;
  float qn[4];
  #pragma unroll
  for (int j=0;j<4;j++) qn[j] = q[j]*invsp - qe[h*D_ + d0 + j];
  const float* tk = tokt + (long)h*9*D_ + d0;
  #pragma unroll
  for (int k=0;k<9;k++){
    f4v tv = *(const f4v*)(tk + k*D_);
    float tok = qn[0]*tv[0] + qn[1]*tv[1] + qn[2]*tv[2] + qn[3]*tv[3];
    #pragma unroll
    for (int off=1; off<8; off<<=1) tok += __shfl_xor(tok, off);
    float wl = tok + tbias[h*9+k] + __expf(sl[k] - 8.f)*invL;
    int di = k/3-1, dj = k%3-1;
    int yy = hy+di, xx = wx+dj;
    if (yy>=0 && yy<H_ && xx>=0 && xx<W_){                     // OOB v_l -> contributes 0
      s4v v4 = *(const s4v*)(kvb + (long)(yy*W_+xx)*FW + 128);
      #pragma unroll
      for (int j=0;j<4;j++) out[j] = fmaf(wl, cvt(((const bf16*)&v4)[j]), out[j]);
    }
  }
  bf16 o4[4];
  #pragma unroll
  for (int j=0;j<4;j++) o4[j] = __float2bfloat16(out[j]);
  *(s4v*)(xo + ((long)(b*N_ + n))*C_ + h*D_ + d0) = *(const s4v*)o4;
}

// ---------------- depthwise 3x3 + bias + gelu, gated -> g ROWS (n, 352) -------------
__global__ __launch_bounds__(256)
void dwconv_kernel(const bf16* __restrict__ f1, const float* __restrict__ dww,
                   const float* __restrict__ dwb, bf16* __restrict__ g)
{
  __shared__ bf16 sg[32*72];                   // 32 c x 64 n, stride 72 (4-way on write)
  int bx = blockIdx.x;                         // ((b*11 + cg)*49 + ntile)
  int ntile = bx % 49;
  int cg    = (bx / 49) % 11;
  int b     = bx / (49*11);
  int t = threadIdx.x;
  f1 += (long)b*2*HF_*N_;
  {
    int c_local = t & 31, chun = t >> 5;
    int c = cg*32 + c_local;
    int n0 = ntile*64 + chun*8;
    int y = n0 / W_, x0 = n0 % W_;             // chunks never cross rows (8 | 56)
    bf16 o8[8];
    if (c < HF_){
      const bf16* ap = f1 + (long)c*N_;
      float acc[8];
      #pragma unroll
      for (int j=0;j<8;j++) acc[j] = dwb[c];
      #pragma unroll
      for (int dy=-1; dy<=1; dy++){
        int yy = y + dy;
        if (yy < 0 || yy >= H_) continue;
        int base = yy*W_ + x0;
        s8v mid = *(const s8v*)(ap + base);    // 16B aligned (112|yy*W_*2, 16|x0*2)
        float wnd[10];
        wnd[0] = (x0 > 0)      ? cvt(ap[base-1]) : 0.f;
        #pragma unroll
        for (int j=0;j<8;j++) wnd[1+j] = cvt(((const bf16*)&mid)[j]);
        wnd[9] = (x0 + 8 < W_) ? cvt(ap[base+8]) : 0.f;
        float k0 = dww[c*9 + (dy+1)*3    ];
        float k1 = dww[c*9 + (dy+1)*3 + 1];
        float k2 = dww[c*9 + (dy+1)*3 + 2];
        #pragma unroll
        for (int j=0;j<8;j++)
          acc[j] = fmaf(k0, wnd[j], fmaf(k1, wnd[j+1], fmaf(k2, wnd[j+2], acc[j])));
      }
      s8v g8 = *(const s8v*)(f1 + (long)(HF_+c)*N_ + n0);
      #pragma unroll
      for (int j=0;j<8;j++)
        o8[j] = __float2bfloat16(gelu_exact(acc[j]) * cvt(((const bf16*)&g8)[j]));
    } else {
      #pragma unroll
      for (int j=0;j<8;j++) o8[j] = __float2bfloat16(0.f);
    }
    *(s8v*)(&sg[c_local*72 + chun*8]) = *(const s8v*)o8;
  }
  __syncthreads();
  {
    int n_local = t >> 2, c0 = (t & 3)*8;
    bf16 o8[8];
    #pragma unroll
    for (int j=0;j<8;j++) o8[j] = sg[(c0+j)*72 + n_local];
    *(s8v*)(g + (long)b*N_*KF2 + (long)(ntile*64 + n_local)*KF2 + cg*32 + c0)
        = *(const s8v*)o8;
  }
}

// ---------------- launcher ----------------
extern "C" void kernel_launch(void* const* d_in, const int* in_sizes, int n_in,
                              void* d_out, int out_size, void* d_ws, size_t ws_size,
                              hipStream_t stream)
{
  (void)in_sizes; (void)n_in; (void)out_size; (void)ws_size;
  const float* x_in      = (const float*)d_in[0];
  const float* norm1_w   = (const float*)d_in[1];
  const float* norm1_b   = (const float*)d_in[2];
  const float* q_w       = (const float*)d_in[3];
  const float* q_b       = (const float*)d_in[4];
  const float* kv_w      = (const float*)d_in[5];
  const float* kv_b      = (const float*)d_in[6];
  const float* temp      = (const float*)d_in[7];
  const float* qe        = (const float*)d_in[8];
  const float* tokens    = (const float*)d_in[9];
  const float* tbias     = (const float*)d_in[10];
  const float* sr_w      = (const float*)d_in[11];
  const float* sr_b      = (const float*)d_in[12];
  const float* pln_w     = (const float*)d_in[13];
  const float* pln_b     = (const float*)d_in[14];
  const float* proj_w    = (const float*)d_in[15];
  const float* proj_b    = (const float*)d_in[16];
  const float* norm2_w   = (const float*)d_in[17];
  const float* norm2_b   = (const float*)d_in[18];
  const float* fc1_w     = (const float*)d_in[19];
  const float* fc1_b     = (const float*)d_in[20];
  const float* dw_w      = (const float*)d_in[21];
  const float* dw_b      = (const float*)d_in[22];
  const float* fc2_w     = (const float*)d_in[23];
  const float* fc2_b     = (const float*)d_in[24];

  char* w8 = (char*)d_ws;
  bf16*  fused   = (bf16*)(w8 + 0);
  float* x2      = (float*)(w8 + 0);
  bf16*  y2      = (bf16*)(w8 + 3211264);
  bf16*  f1b     = (bf16*)(w8 + 4816896);
  bf16*  qs      = (bf16*)(w8 + 6422528);
  bf16*  k_p     = (bf16*)(w8 + 9633792);
  bf16*  v_p     = (bf16*)(w8 + 11239424);
  bf16*  Opart   = (bf16*)(w8 + 13045056);
  bf16*  g_rows  = (bf16*)(w8 + 32312640);
  bf16*  wbase   = (bf16*)(w8 + 36728128);
  float* fbias   = (float*)(w8 + 37156672);
  float* tokt    = (float*)(w8 + 37158720);
  bf16*  y       = f1b;                         // LN1 output rows (dead before f1b use)
  bf16*  xo      = (bf16*)d_out;
  float* Lpart   = (float*)((char*)d_out + 1605632);
  bf16*  proj_wb = wbase + 65536;
  bf16*  fc1_wb  = wbase + 81920;
  bf16*  fc2_wb  = wbase + 169216;

  // 0. weights -> bf16 (vectorized) + bias + tokens^T + tiled LN1 (216+392 blocks)
  head_kernel<<<216 + NTILE, 256, 0, stream>>>(
      q_w, kv_w, sr_w, proj_w, fc1_w, fc2_w, q_b, kv_b, sr_b, tokens,
      wbase, fbias, tokt, x_in, norm1_w, norm1_b, y);
  // 2. fused = y @ [q_w; kv_w; sr_w]^T + bias
  gemm_mfma<128, 6, bf16, 128, 128, 2><<<dim3(8,49), 256, 0, stream>>>(
      y, wbase, fbias, nullptr, fused, ROWS_, FW, 0,0,0,0, qe, temp, qs, nullptr);
  // 4. kvp = LN_pln(fused sr cols) @ kv_w^T + kv_b
  gemm_mfma<128, 7, bf16, 64, FW><<<dim3(4,98), 256, 0, stream>>>(
      fused + 384, wbase + 16384, kv_b, nullptr, (bf16*)nullptr, ROWS_, 256, 0,0,0,0,
      pln_w, pln_b, k_p, v_p);
  // 5. pool-attention partials (2 chains/wave, 25-wide q-grid: 1600 blocks = 6.25/CU)
  attn_part_kernel<<<dim3(25,8,KSP), 256, 0, stream>>>(qs, k_p, v_p, Opart, Lpart);
  // 6. combine + local 3x3 + tokens -> xo
  attn_combine_kernel<<<GQ_*8/256, 256, 0, stream>>>(Opart, Lpart, qs, fused,
                                                     qe, temp, tokt, tbias, xo);
  // 7. x2 = x_in + (xo @ proj_w^T + proj_b)
  gemm_mfma<128, 4, float, 16><<<dim3(2,392), 64, 0, stream>>>(
      xo, proj_wb, proj_b, x_in, x2, ROWS_, 128, 0,0,0,0, nullptr, nullptr, nullptr, nullptr);
  // 8. y2 = LN2(x2)
  ln_tile_kernel<<<NTILE, 256, 0, stream>>>(x2, norm2_w, norm2_b, y2);
  // 9. MLP
  gemm_mfma<128, 3, bf16, 128, 128, 2><<<dim3(49,6,B_), 256, 0, stream>>>(
      fc1_wb, y2, fc1_b, nullptr, f1b, 2*HF_, N_,
      0, (long)N_*C_, (long)2*HF_*N_, 0, nullptr, nullptr, nullptr, nullptr);
  dwconv_kernel<<<B_*11*49, 256, 0, stream>>>(f1b, dw_w, dw_b, g_rows);
  gemm_mfma<KF2, 5, float, 16><<<dim3(49,8,B_), 64, 0, stream>>>(
      fc2_wb, g_rows, fc2_b, x2, (float*)d_out, C_, N_,
      0, (long)N_*KF2, (long)C_*N_, (long)C_*N_, nullptr, nullptr, nullptr, nullptr);
}

// Round 16
// 218.927 us; speedup vs baseline: 1.2522x; 1.0341x over previous
//
#include <hip/hip_runtime.h>
#include <hip/hip_bf16.h>

typedef __hip_bfloat16 bf16;
typedef short s8v __attribute__((ext_vector_type(8)));   // 8 bf16 = 4 VGPR MFMA frag
typedef short s4v __attribute__((ext_vector_type(4)));   // 4 bf16 = 8B packed store
typedef float f4v __attribute__((ext_vector_type(4)));   // 4 fp32 MFMA acc

#define DEVI __device__ __forceinline__

DEVI float cvt(float x){ return x; }
DEVI float cvt(bf16 x){ return __bfloat162float(x); }

DEVI void stg(float* p, float v){ *p = v; }
DEVI void stg(bf16* p, float v){ *p = __float2bfloat16(v); }

DEVI float gelu_exact(float x){
  return 0.5f*x*(1.0f + erff(x*0.70710678118654752440f));
}

// problem constants
constexpr int B_ = 2, C_ = 128, H_ = 56, W_ = 56, N_ = 3136, NH_ = 4, D_ = 32, HF_ = 341;
constexpr int ROWS_ = B_*N_;             // 6272
constexpr int KF2 = 352;                 // fc2 K padded 341 -> 352 (11*32)
constexpr int GQ_ = NH_*B_*N_;           // 25088 (bh*N + n)
constexpr int FW = 512;                  // fused qkv+sr width (q 0..128 | kv 128..384 | sr 384..512)
constexpr int KSP = 8;                   // attention key splits
constexpr int SPLIT = 384;               // keys per split (6 tiles; last split gets 448)
constexpr int NTILE = 392;               // LN tiles (6272/16)
constexpr float LOG2E = 1.4426950408889634f;
constexpr float E8L2  = 11.541560327111707f;   // 8*log2(e); exp(s-8) = exp2(s*log2e - E8L2)

// ---------------- tiled plane->row LayerNorm (16 rows x 128 ch per block) ----------
DEVI void ln_tile_body(int tile, int t, const float* __restrict__ x,
                       const float* __restrict__ w, const float* __restrict__ bia,
                       bf16* __restrict__ y, float* sm /*128*17*/, float* st /*32*/)
{
  int b = tile / 196, nb = (tile % 196) * 16;
  // phase 1: load 16 rows x 128 ch, thread (c,half) -> 8 consecutive n (two float4)
  {
    int c = t >> 1, half = t & 1;
    const float* xp = x + ((long)b*C_ + c)*N_ + nb + half*8;
    f4v v0 = *(const f4v*)xp;
    f4v v1 = *(const f4v*)(xp + 4);
    #pragma unroll
    for (int j=0;j<4;j++){
      sm[c*17 + half*8 + j    ] = v0[j];
      sm[c*17 + half*8 + 4 + j] = v1[j];
    }
  }
  __syncthreads();
  // phase 2: row stats; 16 threads per row, each sums 8 channels, xor-reduce low 4 bits
  {
    int i = t >> 4, k = t & 15;
    float s = 0.f, ss = 0.f;
    #pragma unroll
    for (int u=0;u<8;u++){
      float v = sm[(k + u*16)*17 + i];
      s += v; ss = fmaf(v,v,ss);
    }
    #pragma unroll
    for (int off=1; off<16; off<<=1){
      s  += __shfl_xor(s,  off);
      ss += __shfl_xor(ss, off);
    }
    if (k == 0){
      float mu  = s*(1.0f/128.0f);
      float var = fmaxf(ss*(1.0f/128.0f) - mu*mu, 0.f);
      st[i]      = mu;
      st[16 + i] = rsqrtf(var + 1e-5f);
    }
  }
  __syncthreads();
  // phase 3: write row-major bf16, thread (i, c0/8) -> 16B store
  {
    int i = t >> 4, c0 = (t & 15)*8;
    float mu = st[i], inv = st[16 + i];
    bf16 o8[8];
    #pragma unroll
    for (int j=0;j<8;j++){
      int c = c0 + j;
      o8[j] = __float2bfloat16((sm[c*17 + i] - mu)*inv*w[c] + bia[c]);
    }
    *(s8v*)(y + ((long)(b*N_ + nb + i))*C_ + c0) = *(const s8v*)o8;
  }
}

__global__ __launch_bounds__(256)
void ln_tile_kernel(const float* __restrict__ x, const float* __restrict__ w,
                    const float* __restrict__ bia, bf16* __restrict__ y)
{
  __shared__ float sm[128*17];
  __shared__ float st[32];
  ln_tile_body(blockIdx.x, threadIdx.x, x, w, bia, y, sm, st);
}

// ---------------- HEAD: vectorized weight conversion + bias + tokens^T + tiled LN1 --
__global__ __launch_bounds__(256)
void head_kernel(const float* __restrict__ q_w, const float* __restrict__ kv_w,
                 const float* __restrict__ sr_w, const float* __restrict__ proj_w,
                 const float* __restrict__ fc1_w, const float* __restrict__ fc2_w,
                 const float* __restrict__ q_b, const float* __restrict__ kv_b,
                 const float* __restrict__ sr_b, const float* __restrict__ tokens,
                 bf16* __restrict__ out, float* __restrict__ bias_out,
                 float* __restrict__ tokt,
                 const float* __restrict__ x_in, const float* __restrict__ n1w,
                 const float* __restrict__ n1b, bf16* __restrict__ y)
{
  __shared__ float sm[128*17];
  __shared__ float st[32];
  if (blockIdx.x >= 216){
    ln_tile_body(blockIdx.x - 216, threadIdx.x, x_in, n1w, n1b, y, sm, st);
    return;
  }
  int t = blockIdx.x*256 + threadIdx.x;
  if (t < 42304){
    int t0 = t*4;
    const float* src;
    if      (t0 <  16384) src = q_w    + t0;
    else if (t0 <  49152) src = kv_w   + (t0-16384);
    else if (t0 <  65536) src = sr_w   + (t0-49152);
    else if (t0 <  81920) src = proj_w + (t0-65536);
    else                  src = fc1_w  + (t0-81920);
    f4v v = *(const f4v*)src;
    bf16 o4[4];
    #pragma unroll
    for (int j=0;j<4;j++) o4[j] = __float2bfloat16(v[j]);
    *(s4v*)(out + t0) = *(const s4v*)o4;
  } else if (t < 53568){
    int i = (t - 42304)*4;                  // fc2 region, 4 elems within one m
    int m = i / KF2, kp = i % KF2;
    bf16 o4[4];
    #pragma unroll
    for (int j=0;j<4;j++)
      o4[j] = __float2bfloat16((kp+j < HF_) ? fc2_w[m*HF_ + kp + j] : 0.f);
    *(s4v*)(out + 169216 + i) = *(const s4v*)o4;
  } else if (t < 54080){
    int i = t - 53568;
    float bv = (i < 128) ? q_b[i] : (i < 384) ? kv_b[i-128] : sr_b[i-384];
    bias_out[i] = bv;
  } else if (t < 55232){
    int i = t - 54080;                      // (h*9+k)*32 + d
    int hk = i >> 5, d = i & 31;
    int h = hk / 9, k = hk - h*9;
    tokt[i] = tokens[(h*D_ + d)*9 + k];
  }
}

// ---------------- LDS-free MFMA GEMM (batched via blockIdx.z strides) ----------------
template<int KT, int MODE, typename TC, int BM=64, int LDA=KT, int NCH=1>
__global__ __launch_bounds__(256)
void gemm_mfma(const bf16* __restrict__ A, const bf16* __restrict__ B,
               const float* __restrict__ bias, const float* __restrict__ res,
               TC* __restrict__ Cm, int M, int Nn,
               long sA, long sB, long sC, long sR,
               const float* __restrict__ qe, const float* __restrict__ temp,
               bf16* __restrict__ aux0, bf16* __restrict__ aux1)
{
  A  += (long)blockIdx.z * sA;
  B  += (long)blockIdx.z * sB;
  Cm += (long)blockIdx.z * sC;
  if (res) res += (long)blockIdx.z * sR;
  int lane = threadIdx.x & 63, w = threadIdx.x >> 6;
  int m = lane & 15, quad = lane >> 4;
  int n0 = blockIdx.x*64, m0 = blockIdx.y*BM;
  const bf16* ap[NCH];
  #pragma unroll
  for (int cc=0; cc<NCH; cc++){
    int ar = m0 + cc*64 + w*16 + m;
    if (ar >= M) ar = M-1;                      // clamp loads; stores guarded
    ap[cc] = A + (long)ar*LDA + quad*8;
  }
  const bf16* bp = B + (long)(n0 + m)*KT + quad*8;
  s8v a4[KT/32];
  if (MODE==7){
    // in-register LayerNorm of the A rows (stats over 128 via quad-axis shuffles)
    float s=0.f, ssum=0.f;
    #pragma unroll
    for (int i=0;i<KT/32;i++){
      a4[i] = *(const s8v*)(ap[0] + i*32);
      #pragma unroll
      for (int j=0;j<8;j++){
        float v = cvt(((const bf16*)&a4[i])[j]);
        s += v; ssum = fmaf(v,v,ssum);
      }
    }
    s    += __shfl_xor(s,16);    s    += __shfl_xor(s,32);
    ssum += __shfl_xor(ssum,16); ssum += __shfl_xor(ssum,32);
    float mu  = s*(1.0f/128.0f);
    float var = fmaxf(ssum*(1.0f/128.0f) - mu*mu, 0.f);
    float inv = rsqrtf(var + 1e-5f);
    #pragma unroll
    for (int i=0;i<KT/32;i++){
      #pragma unroll
      for (int j=0;j<8;j++){
        int c = i*32 + quad*8 + j;
        float v = cvt(((const bf16*)&a4[i])[j]);
        ((bf16*)&a4[i])[j] = __float2bfloat16((v-mu)*inv*qe[c] + temp[c]);
      }
    }
  }
  f4v acc[NCH][4];
  #pragma unroll
  for (int cc=0; cc<NCH; cc++)
    #pragma unroll
    for (int s=0;s<4;s++) acc[cc][s] = (f4v){0.f,0.f,0.f,0.f};
  __builtin_amdgcn_s_setprio(1);
  #pragma unroll
  for (int k0 = 0; k0 < KT; k0 += 32){
    s8v bf[4];
    #pragma unroll
    for (int s=0;s<4;s++) bf[s] = *(const s8v*)(bp + (long)s*16*KT + k0);
    #pragma unroll
    for (int cc=0; cc<NCH; cc++){
      s8v af = (MODE==7) ? a4[k0/32] : *(const s8v*)(ap[cc] + k0);
      #pragma unroll
      for (int s=0;s<4;s++)
        acc[cc][s] = __builtin_amdgcn_mfma_f32_16x16x32_bf16(af, bf[s], acc[cc][s], 0, 0, 0);
    }
  }
  __builtin_amdgcn_s_setprio(0);
  // ---- specialized epilogues (M is an exact multiple of 64 for modes 6/7) ----
  if ((MODE==6 || MODE==7) && blockIdx.x < 2){
    // normalized section (q for mode 6, k for mode 7); head pair hA,hB
    int hA = blockIdx.x*2, hB = hA+1;
    float spA = 0.f, spB = 0.f;
    if (MODE==6){
      spA = log1pf(expf(temp[hA])) * LOG2E;     // qs carries log2e for exp2-softmax
      spB = log1pf(expf(temp[hB])) * LOG2E;
    }
    #pragma unroll
    for (int cc=0; cc<NCH; cc++){
      #pragma unroll
      for (int r=0;r<4;r++){
        float v4[4];
        #pragma unroll
        for (int s=0;s<4;s++) v4[s] = acc[cc][s][r] + bias[n0 + s*16 + m];
        float ssA = v4[0]*v4[0] + v4[1]*v4[1];
        float ssB = v4[2]*v4[2] + v4[3]*v4[3];
        #pragma unroll
        for (int off=1; off<16; off<<=1){
          ssA += __shfl_xor(ssA, off);
          ssB += __shfl_xor(ssB, off);
        }
        float invA = 1.f/fmaxf(sqrtf(ssA), 1e-12f);
        float invB = 1.f/fmaxf(sqrtf(ssB), 1e-12f);
        int gm = m0 + cc*64 + w*16 + quad*4 + r;
        int b = gm / N_, n = gm % N_;
        #pragma unroll
        for (int s=0;s<4;s++){
          int h = (s<2) ? hA : hB;
          int d = (s&1)*16 + m;
          float v = v4[s] * ((s<2) ? invA : invB);
          if (MODE==6) v = (v + qe[h*D_ + d]) * ((s<2) ? spA : spB);
          aux0[((long)(b*NH_+h)*N_ + n)*D_ + d] = __float2bfloat16(v);
        }
      }
    }
    return;
  }
  if (MODE==7){                                 // v section (bx 2,3) -> v_p planes (bf16)
    int gm0 = m0 + w*16 + quad*4;
    int b = gm0 / N_, nb = gm0 % N_;            // 4 consecutive rows share b (tiles of 4)
    #pragma unroll
    for (int s=0;s<4;s++){
      int h = (blockIdx.x-2)*2 + (s>>1);
      int d = (s&1)*16 + m;
      bf16 p4[4];
      #pragma unroll
      for (int r=0;r<4;r++) p4[r] = __float2bfloat16(acc[0][s][r] + bias[n0 + s*16 + m]);
      *(s4v*)(aux1 + ((long)(b*NH_+h)*D_ + d)*N_ + nb) = *(const s4v*)p4;
    }
    return;
  }
  // ---- generic epilogue ----
  #pragma unroll
  for (int cc=0; cc<NCH; cc++){
    int m0c = m0 + cc*64;
    #pragma unroll
    for (int s=0;s<4;s++){
      int gn = n0 + s*16 + m;
      #pragma unroll
      for (int r=0;r<4;r++){
        int gm = m0c + w*16 + quad*4 + r;
        if (gm >= M) continue;
        float v = acc[cc][s][r];
        if (MODE==1 || MODE==4 || MODE==6) v += bias[gn];
        else                               v += bias[gm];
        if (MODE==6 && gn >= 384) v = gelu_exact(v);
        if (MODE==4 || MODE==5) v += res[(long)gm*Nn + gn];
        stg(&Cm[(long)gm*Nn + gn], v);
      }
    }
  }
}

// ---------------- MFMA pool-attention PARTIAL (fully LDS-free, all-x32, prefetched) -
// r16: REVERT to the verified r13 config -- 4 chains/wave, grid (13,8,8).
// r15's 2-chain/25-grid variant REGRESSED +5.3us: the 4 independent chains are the
// ILP that hides the QK->exp->PV dependency latency (scheduler interleaves ch1's
// MFMAs under ch0's exps); halving them hurt more than 2x waves helped, and K/V
// L2 traffic doubled. Occupancy levers on this kernel are now doubly falsified
// (r8 KSP-null, r15 negative) -- 4-chain ILP is the binding resource.
__global__ __launch_bounds__(256)
void attn_part_kernel(const bf16* __restrict__ qs_, const bf16* __restrict__ kp_,
                      const bf16* __restrict__ vp_,
                      bf16* __restrict__ Op, float* __restrict__ Lp)
{
  int bh = blockIdx.y;
  int z  = blockIdx.z;
  int lane = threadIdx.x & 63;
  int w    = threadIdx.x >> 6;
  int m    = lane & 15, quad = lane >> 4;
  int base = blockIdx.x*256 + w*16;

  s8v af[4]; bool hasQ[4];
  #pragma unroll
  for (int ch=0; ch<4; ch++){
    int qq = base + ch*64;
    hasQ[ch] = (qq < N_);
    af[ch] = *(const s8v*)(qs_ + ((long)bh*N_ + (hasQ[ch] ? qq : base) + m)*D_ + quad*8);
  }
  const bf16* kpb = kp_ + (long)bh*N_*D_;
  const bf16* vpb = vp_ + (long)bh*D_*N_;
  int kperm = (m & 3) + 8*(m >> 2);            // permuted key row for this lane's A-rows
  const f4v CINIT = {-E8L2, -E8L2, -E8L2, -E8L2};
  f4v o0[4], o1[4];
  float l[4];
  #pragma unroll
  for (int ch=0; ch<4; ch++){
    o0[ch] = (f4v){0.f,0.f,0.f,0.f}; o1[ch] = (f4v){0.f,0.f,0.f,0.f};
    l[ch] = 0.f;
  }

  auto loadKV = [&](s8v* kf, s8v* vf, int t){
    kf[0] = *(const s8v*)(kpb + (long)(t + kperm     )*D_ + quad*8);
    kf[1] = *(const s8v*)(kpb + (long)(t + kperm +  4)*D_ + quad*8);
    kf[2] = *(const s8v*)(kpb + (long)(t + kperm + 32)*D_ + quad*8);
    kf[3] = *(const s8v*)(kpb + (long)(t + kperm + 36)*D_ + quad*8);
    vf[0] = *(const s8v*)(vpb + (long)(m     )*N_ + t      + quad*8);
    vf[1] = *(const s8v*)(vpb + (long)(16 + m)*N_ + t      + quad*8);
    vf[2] = *(const s8v*)(vpb + (long)(m     )*N_ + t + 32 + quad*8);
    vf[3] = *(const s8v*)(vpb + (long)(16 + m)*N_ + t + 32 + quad*8);
  };
  auto compute = [&](const s8v* kf, const s8v* vf){
    __builtin_amdgcn_s_setprio(1);
    #pragma unroll
    for (int ch=0; ch<4; ch++){
      f4v c[4];
      #pragma unroll
      for (int s=0;s<4;s++)
        c[s] = __builtin_amdgcn_mfma_f32_16x16x32_bf16(kf[s], af[ch], CINIT, 0, 0, 0);
      bf16 p8a[8], p8b[8];
      float ls = 0.f;
      #pragma unroll
      for (int r=0;r<4;r++){
        float ea = __builtin_amdgcn_exp2f(c[0][r]);   // keys 8q+r
        float eb = __builtin_amdgcn_exp2f(c[1][r]);   // keys 8q+4+r
        float ec = __builtin_amdgcn_exp2f(c[2][r]);   // +32
        float ed = __builtin_amdgcn_exp2f(c[3][r]);
        ls += (ea+eb) + (ec+ed);
        p8a[r] = __float2bfloat16(ea); p8a[4+r] = __float2bfloat16(eb);
        p8b[r] = __float2bfloat16(ec); p8b[4+r] = __float2bfloat16(ed);
      }
      l[ch] += ls;
      s8v pa = *(const s8v*)p8a, pb = *(const s8v*)p8b;
      o0[ch] = __builtin_amdgcn_mfma_f32_16x16x32_bf16(pa, vf[0], o0[ch], 0, 0, 0);
      o1[ch] = __builtin_amdgcn_mfma_f32_16x16x32_bf16(pa, vf[1], o1[ch], 0, 0, 0);
      o0[ch] = __builtin_amdgcn_mfma_f32_16x16x32_bf16(pb, vf[2], o0[ch], 0, 0, 0);
      o1[ch] = __builtin_amdgcn_mfma_f32_16x16x32_bf16(pb, vf[3], o1[ch], 0, 0, 0);
    }
    __builtin_amdgcn_s_setprio(0);
  };

  int tlo = z*SPLIT, thi = (z==KSP-1) ? N_ : tlo + SPLIT;
  s8v kfA[4], vfA[4], kfB[4], vfB[4];
  int t0 = tlo;
  loadKV(kfA, vfA, t0);
  for (;;){
    if (t0 + 64 < thi) loadKV(kfB, vfB, t0 + 64);
    compute(kfA, vfA);
    t0 += 64;
    if (t0 >= thi) break;
    if (t0 + 64 < thi) loadKV(kfA, vfA, t0 + 64);
    compute(kfB, vfB);
    t0 += 64;
    if (t0 >= thi) break;
  }
  // direct per-lane store: lane(m,quad) reg r holds O[q=quad*4+r][d=m] (o0), [16+m] (o1)
  #pragma unroll
  for (int ch=0; ch<4; ch++){
    if (!hasQ[ch]) continue;
    float lr = l[ch];                          // partial for query m over this quad's keys
    lr += __shfl_xor(lr, 16);
    lr += __shfl_xor(lr, 32);                  // full row sum for query m (replicated)
    long gqBase = (long)bh*N_ + base + ch*64;
    #pragma unroll
    for (int r=0;r<4;r++){
      bf16* op = Op + ((long)z*GQ_ + gqBase + quad*4 + r)*32;
      op[m]      = __float2bfloat16(o0[ch][r]);
      op[16 + m] = __float2bfloat16(o1[ch][r]);
    }
    if (quad == 0) Lp[(long)z*GQ_ + gqBase + m] = lr;
  }
}

// ---------------- combine partials + local 3x3 + learnable tokens -> xo rows --------
// 8 lanes per query; r16: exp(sl[k]-8) cached (was computed twice per k).
__global__ __launch_bounds__(256)
void attn_combine_kernel(const bf16* __restrict__ Op, const float* __restrict__ Lp,
                         const bf16* __restrict__ qs_, const bf16* __restrict__ fused,
                         const float* __restrict__ qe, const float* __restrict__ temp,
                         const float* __restrict__ tokt, const float* __restrict__ tbias,
                         bf16* __restrict__ xo)
{
  int t  = blockIdx.x*256 + threadIdx.x;       // 8 threads per query
  int gq = t >> 3;                             // bh*N + n
  int l8 = t & 7;
  int d0 = l8*4;
  int n = gq % N_; int bh = gq / N_; int h = bh & 3; int b = bh >> 2;
  float out[4] = {0.f,0.f,0.f,0.f};
  // partial-O accumulate (8B per z); Lp: one per lane (KSP == 8-lane group size)
  #pragma unroll
  for (int z=0; z<KSP; z++){
    s4v o4 = *(const s4v*)(Op + ((long)z*GQ_ + gq)*32 + d0);
    #pragma unroll
    for (int j=0;j<4;j++) out[j] += cvt(((const bf16*)&o4)[j]);
  }
  float L = Lp[(long)l8*GQ_ + gq];
  #pragma unroll
  for (int off=1; off<8; off<<=1) L += __shfl_xor(L, off);
  // q chunk (undo the log2e scale baked into qs)
  float q[4];
  {
    s4v q4 = *(const s4v*)(qs_ + (long)gq*D_ + d0);
    #pragma unroll
    for (int j=0;j<4;j++) q[j] = cvt(((const bf16*)&q4)[j]) * 0.6931471805599453f;
  }
  int hy = n / W_, wx = n % W_;
  const bf16* kvb = fused + (long)b*N_*FW + 128 + h*D_ + d0;   // key cols (this lane's d's)
  float el[9];
  #pragma unroll
  for (int k=0;k<9;k++){
    int di = k/3-1, dj = k%3-1;
    int yy = hy+di, xx = wx+dj;
    bool ok = (yy>=0 && yy<H_ && xx>=0 && xx<W_);              // uniform within group
    float dot = 0.f, ss = 0.f;
    if (ok){
      s4v k4 = *(const s4v*)(kvb + (long)(yy*W_+xx)*FW);
      #pragma unroll
      for (int j=0;j<4;j++){
        float kk = cvt(((const bf16*)&k4)[j]);
        dot = fmaf(q[j], kk, dot);
        ss  = fmaf(kk, kk, ss);
      }
    }
    #pragma unroll
    for (int off=1; off<8; off<<=1){
      dot += __shfl_xor(dot, off);
      ss  += __shfl_xor(ss,  off);
    }
    float sk = ok ? dot / fmaxf(sqrtf(ss), 1e-12f) : 0.f;      // OOB: exactly 0
    el[k] = __expf(sk - 8.f);
    L += el[k];
  }
  float invL = 1.f/L;
  #pragma unroll
  for (int j=0;j<4;j++) out[j] *= invL;
  float sp = log1pf(expf(temp[h]));
  float invsp = 1.f/sp;
  float qn[4];
  #pragma unroll
  for (int j=0;j<4;j++) qn[j] = q[j]*invsp - qe[h*D_ + d0 + j];
  const float* tk = tokt + (long)h*9*D_ + d0;
  #pragma unroll
  for (int k=0;k<9;k++){
    f4v tv = *(const f4v*)(tk + k*D_);
    float tok = qn[0]*tv[0] + qn[1]*tv[1] + qn[2]*tv[2] + qn[3]*tv[3];
    #pragma unroll
    for (int off=1; off<8; off<<=1) tok += __shfl_xor(tok, off);
    float wl = tok + tbias[h*9+k] + el[k]*invL;
    int di = k/3-1, dj = k%3-1;
    int yy = hy+di, xx = wx+dj;
    if (yy>=0 && yy<H_ && xx>=0 && xx<W_){                     // OOB v_l -> contributes 0
      s4v v4 = *(const s4v*)(kvb + (long)(yy*W_+xx)*FW + 128);
      #pragma unroll
      for (int j=0;j<4;j++) out[j] = fmaf(wl, cvt(((const bf16*)&v4)[j]), out[j]);
    }
  }
  bf16 o4[4];
  #pragma unroll
  for (int j=0;j<4;j++) o4[j] = __float2bfloat16(out[j]);
  *(s4v*)(xo + ((long)(b*N_ + n))*C_ + h*D_ + d0) = *(const s4v*)o4;
}

// ---------------- depthwise 3x3 + bias + gelu, gated -> g ROWS (n, 352) -------------
__global__ __launch_bounds__(256)
void dwconv_kernel(const bf16* __restrict__ f1, const float* __restrict__ dww,
                   const float* __restrict__ dwb, bf16* __restrict__ g)
{
  __shared__ bf16 sg[32*72];                   // 32 c x 64 n, stride 72 (4-way on write)
  int bx = blockIdx.x;                         // ((b*11 + cg)*49 + ntile)
  int ntile = bx % 49;
  int cg    = (bx / 49) % 11;
  int b     = bx / (49*11);
  int t = threadIdx.x;
  f1 += (long)b*2*HF_*N_;
  {
    int c_local = t & 31, chun = t >> 5;
    int c = cg*32 + c_local;
    int n0 = ntile*64 + chun*8;
    int y = n0 / W_, x0 = n0 % W_;             // chunks never cross rows (8 | 56)
    bf16 o8[8];
    if (c < HF_){
      const bf16* ap = f1 + (long)c*N_;
      float acc[8];
      #pragma unroll
      for (int j=0;j<8;j++) acc[j] = dwb[c];
      #pragma unroll
      for (int dy=-1; dy<=1; dy++){
        int yy = y + dy;
        if (yy < 0 || yy >= H_) continue;
        int base = yy*W_ + x0;
        s8v mid = *(const s8v*)(ap + base);    // 16B aligned (112|yy*W_*2, 16|x0*2)
        float wnd[10];
        wnd[0] = (x0 > 0)      ? cvt(ap[base-1]) : 0.f;
        #pragma unroll
        for (int j=0;j<8;j++) wnd[1+j] = cvt(((const bf16*)&mid)[j]);
        wnd[9] = (x0 + 8 < W_) ? cvt(ap[base+8]) : 0.f;
        float k0 = dww[c*9 + (dy+1)*3    ];
        float k1 = dww[c*9 + (dy+1)*3 + 1];
        float k2 = dww[c*9 + (dy+1)*3 + 2];
        #pragma unroll
        for (int j=0;j<8;j++)
          acc[j] = fmaf(k0, wnd[j], fmaf(k1, wnd[j+1], fmaf(k2, wnd[j+2], acc[j])));
      }
      s8v g8 = *(const s8v*)(f1 + (long)(HF_+c)*N_ + n0);
      #pragma unroll
      for (int j=0;j<8;j++)
        o8[j] = __float2bfloat16(gelu_exact(acc[j]) * cvt(((const bf16*)&g8)[j]));
    } else {
      #pragma unroll
      for (int j=0;j<8;j++) o8[j] = __float2bfloat16(0.f);
    }
    *(s8v*)(&sg[c_local*72 + chun*8]) = *(const s8v*)o8;
  }
  __syncthreads();
  {
    int n_local = t >> 2, c0 = (t & 3)*8;
    bf16 o8[8];
    #pragma unroll
    for (int j=0;j<8;j++) o8[j] = sg[(c0+j)*72 + n_local];
    *(s8v*)(g + (long)b*N_*KF2 + (long)(ntile*64 + n_local)*KF2 + cg*32 + c0)
        = *(const s8v*)o8;
  }
}

// ---------------- launcher ----------------
extern "C" void kernel_launch(void* const* d_in, const int* in_sizes, int n_in,
                              void* d_out, int out_size, void* d_ws, size_t ws_size,
                              hipStream_t stream)
{
  (void)in_sizes; (void)n_in; (void)out_size; (void)ws_size;
  const float* x_in      = (const float*)d_in[0];
  const float* norm1_w   = (const float*)d_in[1];
  const float* norm1_b   = (const float*)d_in[2];
  const float* q_w       = (const float*)d_in[3];
  const float* q_b       = (const float*)d_in[4];
  const float* kv_w      = (const float*)d_in[5];
  const float* kv_b      = (const float*)d_in[6];
  const float* temp      = (const float*)d_in[7];
  const float* qe        = (const float*)d_in[8];
  const float* tokens    = (const float*)d_in[9];
  const float* tbias     = (const float*)d_in[10];
  const float* sr_w      = (const float*)d_in[11];
  const float* sr_b      = (const float*)d_in[12];
  const float* pln_w     = (const float*)d_in[13];
  const float* pln_b     = (const float*)d_in[14];
  const float* proj_w    = (const float*)d_in[15];
  const float* proj_b    = (const float*)d_in[16];
  const float* norm2_w   = (const float*)d_in[17];
  const float* norm2_b   = (const float*)d_in[18];
  const float* fc1_w     = (const float*)d_in[19];
  const float* fc1_b     = (const float*)d_in[20];
  const float* dw_w      = (const float*)d_in[21];
  const float* dw_b      = (const float*)d_in[22];
  const float* fc2_w     = (const float*)d_in[23];
  const float* fc2_b     = (const float*)d_in[24];

  char* w8 = (char*)d_ws;
  bf16*  fused   = (bf16*)(w8 + 0);
  float* x2      = (float*)(w8 + 0);
  bf16*  y2      = (bf16*)(w8 + 3211264);
  bf16*  f1b     = (bf16*)(w8 + 4816896);
  bf16*  qs      = (bf16*)(w8 + 6422528);
  bf16*  k_p     = (bf16*)(w8 + 9633792);
  bf16*  v_p     = (bf16*)(w8 + 11239424);
  bf16*  Opart   = (bf16*)(w8 + 13045056);
  bf16*  g_rows  = (bf16*)(w8 + 32312640);
  bf16*  wbase   = (bf16*)(w8 + 36728128);
  float* fbias   = (float*)(w8 + 37156672);
  float* tokt    = (float*)(w8 + 37158720);
  bf16*  y       = f1b;                         // LN1 output rows (dead before f1b use)
  bf16*  xo      = (bf16*)d_out;
  float* Lpart   = (float*)((char*)d_out + 1605632);
  bf16*  proj_wb = wbase + 65536;
  bf16*  fc1_wb  = wbase + 81920;
  bf16*  fc2_wb  = wbase + 169216;

  // 0. weights -> bf16 (vectorized) + bias + tokens^T + tiled LN1 (216+392 blocks)
  head_kernel<<<216 + NTILE, 256, 0, stream>>>(
      q_w, kv_w, sr_w, proj_w, fc1_w, fc2_w, q_b, kv_b, sr_b, tokens,
      wbase, fbias, tokt, x_in, norm1_w, norm1_b, y);
  // 2. fused = y @ [q_w; kv_w; sr_w]^T + bias
  gemm_mfma<128, 6, bf16, 128, 128, 2><<<dim3(8,49), 256, 0, stream>>>(
      y, wbase, fbias, nullptr, fused, ROWS_, FW, 0,0,0,0, qe, temp, qs, nullptr);
  // 4. kvp = LN_pln(fused sr cols) @ kv_w^T + kv_b
  gemm_mfma<128, 7, bf16, 64, FW><<<dim3(4,98), 256, 0, stream>>>(
      fused + 384, wbase + 16384, kv_b, nullptr, (bf16*)nullptr, ROWS_, 256, 0,0,0,0,
      pln_w, pln_b, k_p, v_p);
  // 5. pool-attention partials (4 chains/wave, grid (13,8,8) -- verified best)
  attn_part_kernel<<<dim3(13,8,KSP), 256, 0, stream>>>(qs, k_p, v_p, Opart, Lpart);
  // 6. combine + local 3x3 + tokens -> xo
  attn_combine_kernel<<<GQ_*8/256, 256, 0, stream>>>(Opart, Lpart, qs, fused,
                                                     qe, temp, tokt, tbias, xo);
  // 7. x2 = x_in + (xo @ proj_w^T + proj_b)
  gemm_mfma<128, 4, float, 16><<<dim3(2,392), 64, 0, stream>>>(
      xo, proj_wb, proj_b, x_in, x2, ROWS_, 128, 0,0,0,0, nullptr, nullptr, nullptr, nullptr);
  // 8. y2 = LN2(x2)
  ln_tile_kernel<<<NTILE, 256, 0, stream>>>(x2, norm2_w, norm2_b, y2);
  // 9. MLP
  gemm_mfma<128, 3, bf16, 128, 128, 2><<<dim3(49,6,B_), 256, 0, stream>>>(
      fc1_wb, y2, fc1_b, nullptr, f1b, 2*HF_, N_,
      0, (long)N_*C_, (long)2*HF_*N_, 0, nullptr, nullptr, nullptr, nullptr);
  dwconv_kernel<<<B_*11*49, 256, 0, stream>>>(f1b, dw_w, dw_b, g_rows);
  gemm_mfma<KF2, 5, float, 16><<<dim3(49,8,B_), 64, 0, stream>>>(
      fc2_wb, g_rows, fc2_b, x2, (float*)d_out, C_, N_,
      0, (long)N_*KF2, (long)C_*N_, (long)C_*N_, nullptr, nullptr, nullptr, nullptr);
}

// Round 17
// 217.753 us; speedup vs baseline: 1.2589x; 1.0054x over previous
//
#include <hip/hip_runtime.h>
#include <hip/hip_bf16.h>

typedef __hip_bfloat16 bf16;
typedef short s8v __attribute__((ext_vector_type(8)));   // 8 bf16 = 4 VGPR MFMA frag
typedef short s4v __attribute__((ext_vector_type(4)));   // 4 bf16 = 8B packed store
typedef float f4v __attribute__((ext_vector_type(4)));   // 4 fp32 MFMA acc

#define DEVI __device__ __forceinline__

DEVI float cvt(float x){ return x; }
DEVI float cvt(bf16 x){ return __bfloat162float(x); }

DEVI void stg(float* p, float v){ *p = v; }
DEVI void stg(bf16* p, float v){ *p = __float2bfloat16(v); }

DEVI float gelu_exact(float x){
  return 0.5f*x*(1.0f + erff(x*0.70710678118654752440f));
}

// problem constants
constexpr int B_ = 2, C_ = 128, H_ = 56, W_ = 56, N_ = 3136, NH_ = 4, D_ = 32, HF_ = 341;
constexpr int ROWS_ = B_*N_;             // 6272
constexpr int KF2 = 352;                 // fc2 K padded 341 -> 352 (11*32)
constexpr int GQ_ = NH_*B_*N_;           // 25088 (bh*N + n)
constexpr int FW = 512;                  // fused qkv+sr width (q 0..128 | kv 128..384 | sr 384..512)
constexpr int KSP = 8;                   // attention key splits
constexpr int SPLIT = 384;               // keys per split (6 tiles; last split gets 448)
constexpr int NTILE = 392;               // LN tiles (6272/16)
constexpr float LOG2E = 1.4426950408889634f;
constexpr float E8L2  = 11.541560327111707f;   // 8*log2(e); exp(s-8) = exp2(s*log2e - E8L2)

// ---------------- tiled plane->row LayerNorm (16 rows x 128 ch per block) ----------
DEVI void ln_tile_body(int tile, int t, const float* __restrict__ x,
                       const float* __restrict__ w, const float* __restrict__ bia,
                       bf16* __restrict__ y, float* sm /*128*17*/, float* st /*32*/)
{
  int b = tile / 196, nb = (tile % 196) * 16;
  // phase 1: load 16 rows x 128 ch, thread (c,half) -> 8 consecutive n (two float4)
  {
    int c = t >> 1, half = t & 1;
    const float* xp = x + ((long)b*C_ + c)*N_ + nb + half*8;
    f4v v0 = *(const f4v*)xp;
    f4v v1 = *(const f4v*)(xp + 4);
    #pragma unroll
    for (int j=0;j<4;j++){
      sm[c*17 + half*8 + j    ] = v0[j];
      sm[c*17 + half*8 + 4 + j] = v1[j];
    }
  }
  __syncthreads();
  // phase 2: row stats; 16 threads per row, each sums 8 channels, xor-reduce low 4 bits
  {
    int i = t >> 4, k = t & 15;
    float s = 0.f, ss = 0.f;
    #pragma unroll
    for (int u=0;u<8;u++){
      float v = sm[(k + u*16)*17 + i];
      s += v; ss = fmaf(v,v,ss);
    }
    #pragma unroll
    for (int off=1; off<16; off<<=1){
      s  += __shfl_xor(s,  off);
      ss += __shfl_xor(ss, off);
    }
    if (k == 0){
      float mu  = s*(1.0f/128.0f);
      float var = fmaxf(ss*(1.0f/128.0f) - mu*mu, 0.f);
      st[i]      = mu;
      st[16 + i] = rsqrtf(var + 1e-5f);
    }
  }
  __syncthreads();
  // phase 3: write row-major bf16, thread (i, c0/8) -> 16B store
  {
    int i = t >> 4, c0 = (t & 15)*8;
    float mu = st[i], inv = st[16 + i];
    bf16 o8[8];
    #pragma unroll
    for (int j=0;j<8;j++){
      int c = c0 + j;
      o8[j] = __float2bfloat16((sm[c*17 + i] - mu)*inv*w[c] + bia[c]);
    }
    *(s8v*)(y + ((long)(b*N_ + nb + i))*C_ + c0) = *(const s8v*)o8;
  }
}

__global__ __launch_bounds__(256)
void ln_tile_kernel(const float* __restrict__ x, const float* __restrict__ w,
                    const float* __restrict__ bia, bf16* __restrict__ y)
{
  __shared__ float sm[128*17];
  __shared__ float st[32];
  ln_tile_body(blockIdx.x, threadIdx.x, x, w, bia, y, sm, st);
}

// ---------------- HEAD: vectorized weight conversion + bias + tokens^T + tiled LN1 --
__global__ __launch_bounds__(256)
void head_kernel(const float* __restrict__ q_w, const float* __restrict__ kv_w,
                 const float* __restrict__ sr_w, const float* __restrict__ proj_w,
                 const float* __restrict__ fc1_w, const float* __restrict__ fc2_w,
                 const float* __restrict__ q_b, const float* __restrict__ kv_b,
                 const float* __restrict__ sr_b, const float* __restrict__ tokens,
                 bf16* __restrict__ out, float* __restrict__ bias_out,
                 float* __restrict__ tokt,
                 const float* __restrict__ x_in, const float* __restrict__ n1w,
                 const float* __restrict__ n1b, bf16* __restrict__ y)
{
  __shared__ float sm[128*17];
  __shared__ float st[32];
  if (blockIdx.x >= 216){
    ln_tile_body(blockIdx.x - 216, threadIdx.x, x_in, n1w, n1b, y, sm, st);
    return;
  }
  int t = blockIdx.x*256 + threadIdx.x;
  if (t < 42304){
    int t0 = t*4;
    const float* src;
    if      (t0 <  16384) src = q_w    + t0;
    else if (t0 <  49152) src = kv_w   + (t0-16384);
    else if (t0 <  65536) src = sr_w   + (t0-49152);
    else if (t0 <  81920) src = proj_w + (t0-65536);
    else                  src = fc1_w  + (t0-81920);
    f4v v = *(const f4v*)src;
    bf16 o4[4];
    #pragma unroll
    for (int j=0;j<4;j++) o4[j] = __float2bfloat16(v[j]);
    *(s4v*)(out + t0) = *(const s4v*)o4;
  } else if (t < 53568){
    int i = (t - 42304)*4;                  // fc2 region, 4 elems within one m
    int m = i / KF2, kp = i % KF2;
    bf16 o4[4];
    #pragma unroll
    for (int j=0;j<4;j++)
      o4[j] = __float2bfloat16((kp+j < HF_) ? fc2_w[m*HF_ + kp + j] : 0.f);
    *(s4v*)(out + 169216 + i) = *(const s4v*)o4;
  } else if (t < 54080){
    int i = t - 53568;
    float bv = (i < 128) ? q_b[i] : (i < 384) ? kv_b[i-128] : sr_b[i-384];
    bias_out[i] = bv;
  } else if (t < 55232){
    int i = t - 54080;                      // (h*9+k)*32 + d
    int hk = i >> 5, d = i & 31;
    int h = hk / 9, k = hk - h*9;
    tokt[i] = tokens[(h*D_ + d)*9 + k];
  }
}

// ---------------- LDS-free MFMA GEMM (batched via blockIdx.z strides) ----------------
// MODE 6 (r17): bx<2 -> l2norm q-head -> qs rows; bx in {2,3} -> l2norm K-HEAD
// cols IN-PLACE into fused (reference normalizes k_loc pre-unfold; fused k cols are
// read only by combine, so pre-normalizing deletes combine's per-neighbor ss/sqrt/div).
template<int KT, int MODE, typename TC, int BM=64, int LDA=KT, int NCH=1>
__global__ __launch_bounds__(256)
void gemm_mfma(const bf16* __restrict__ A, const bf16* __restrict__ B,
               const float* __restrict__ bias, const float* __restrict__ res,
               TC* __restrict__ Cm, int M, int Nn,
               long sA, long sB, long sC, long sR,
               const float* __restrict__ qe, const float* __restrict__ temp,
               bf16* __restrict__ aux0, bf16* __restrict__ aux1)
{
  A  += (long)blockIdx.z * sA;
  B  += (long)blockIdx.z * sB;
  Cm += (long)blockIdx.z * sC;
  if (res) res += (long)blockIdx.z * sR;
  int lane = threadIdx.x & 63, w = threadIdx.x >> 6;
  int m = lane & 15, quad = lane >> 4;
  int n0 = blockIdx.x*64, m0 = blockIdx.y*BM;
  const bf16* ap[NCH];
  #pragma unroll
  for (int cc=0; cc<NCH; cc++){
    int ar = m0 + cc*64 + w*16 + m;
    if (ar >= M) ar = M-1;                      // clamp loads; stores guarded
    ap[cc] = A + (long)ar*LDA + quad*8;
  }
  const bf16* bp = B + (long)(n0 + m)*KT + quad*8;
  s8v a4[KT/32];
  if (MODE==7){
    // in-register LayerNorm of the A rows (stats over 128 via quad-axis shuffles)
    float s=0.f, ssum=0.f;
    #pragma unroll
    for (int i=0;i<KT/32;i++){
      a4[i] = *(const s8v*)(ap[0] + i*32);
      #pragma unroll
      for (int j=0;j<8;j++){
        float v = cvt(((const bf16*)&a4[i])[j]);
        s += v; ssum = fmaf(v,v,ssum);
      }
    }
    s    += __shfl_xor(s,16);    s    += __shfl_xor(s,32);
    ssum += __shfl_xor(ssum,16); ssum += __shfl_xor(ssum,32);
    float mu  = s*(1.0f/128.0f);
    float var = fmaxf(ssum*(1.0f/128.0f) - mu*mu, 0.f);
    float inv = rsqrtf(var + 1e-5f);
    #pragma unroll
    for (int i=0;i<KT/32;i++){
      #pragma unroll
      for (int j=0;j<8;j++){
        int c = i*32 + quad*8 + j;
        float v = cvt(((const bf16*)&a4[i])[j]);
        ((bf16*)&a4[i])[j] = __float2bfloat16((v-mu)*inv*qe[c] + temp[c]);
      }
    }
  }
  f4v acc[NCH][4];
  #pragma unroll
  for (int cc=0; cc<NCH; cc++)
    #pragma unroll
    for (int s=0;s<4;s++) acc[cc][s] = (f4v){0.f,0.f,0.f,0.f};
  __builtin_amdgcn_s_setprio(1);
  #pragma unroll
  for (int k0 = 0; k0 < KT; k0 += 32){
    s8v bf[4];
    #pragma unroll
    for (int s=0;s<4;s++) bf[s] = *(const s8v*)(bp + (long)s*16*KT + k0);
    #pragma unroll
    for (int cc=0; cc<NCH; cc++){
      s8v af = (MODE==7) ? a4[k0/32] : *(const s8v*)(ap[cc] + k0);
      #pragma unroll
      for (int s=0;s<4;s++)
        acc[cc][s] = __builtin_amdgcn_mfma_f32_16x16x32_bf16(af, bf[s], acc[cc][s], 0, 0, 0);
    }
  }
  __builtin_amdgcn_s_setprio(0);
  // ---- specialized epilogues (M is an exact multiple of 64 for modes 6/7) ----
  if ((MODE==6 || MODE==7) && blockIdx.x < 2){
    // normalized section (q for mode 6, k for mode 7); head pair hA,hB
    int hA = blockIdx.x*2, hB = hA+1;
    float spA = 0.f, spB = 0.f;
    if (MODE==6){
      spA = log1pf(expf(temp[hA])) * LOG2E;     // qs carries log2e for exp2-softmax
      spB = log1pf(expf(temp[hB])) * LOG2E;
    }
    #pragma unroll
    for (int cc=0; cc<NCH; cc++){
      #pragma unroll
      for (int r=0;r<4;r++){
        float v4[4];
        #pragma unroll
        for (int s=0;s<4;s++) v4[s] = acc[cc][s][r] + bias[n0 + s*16 + m];
        float ssA = v4[0]*v4[0] + v4[1]*v4[1];
        float ssB = v4[2]*v4[2] + v4[3]*v4[3];
        #pragma unroll
        for (int off=1; off<16; off<<=1){
          ssA += __shfl_xor(ssA, off);
          ssB += __shfl_xor(ssB, off);
        }
        float invA = 1.f/fmaxf(sqrtf(ssA), 1e-12f);
        float invB = 1.f/fmaxf(sqrtf(ssB), 1e-12f);
        int gm = m0 + cc*64 + w*16 + quad*4 + r;
        int b = gm / N_, n = gm % N_;
        #pragma unroll
        for (int s=0;s<4;s++){
          int h = (s<2) ? hA : hB;
          int d = (s&1)*16 + m;
          float v = v4[s] * ((s<2) ? invA : invB);
          if (MODE==6) v = (v + qe[h*D_ + d]) * ((s<2) ? spA : spB);
          aux0[((long)(b*NH_+h)*N_ + n)*D_ + d] = __float2bfloat16(v);
        }
      }
    }
    return;
  }
  if (MODE==6 && blockIdx.x >= 2 && blockIdx.x < 4){
    // r17: K columns (gn in [128,256)) -- l2-normalize per head, store into fused.
    // Same per-(row,head) shuffle reduction as the q path (2 s-tiles per head).
    #pragma unroll
    for (int cc=0; cc<NCH; cc++){
      #pragma unroll
      for (int r=0;r<4;r++){
        float v4[4];
        #pragma unroll
        for (int s=0;s<4;s++) v4[s] = acc[cc][s][r] + bias[n0 + s*16 + m];
        float ssA = v4[0]*v4[0] + v4[1]*v4[1];
        float ssB = v4[2]*v4[2] + v4[3]*v4[3];
        #pragma unroll
        for (int off=1; off<16; off<<=1){
          ssA += __shfl_xor(ssA, off);
          ssB += __shfl_xor(ssB, off);
        }
        float invA = 1.f/fmaxf(sqrtf(ssA), 1e-12f);
        float invB = 1.f/fmaxf(sqrtf(ssB), 1e-12f);
        int gm = m0 + cc*64 + w*16 + quad*4 + r;
        #pragma unroll
        for (int s=0;s<4;s++){
          float v = v4[s] * ((s<2) ? invA : invB);
          stg(&Cm[(long)gm*Nn + n0 + s*16 + m], v);
        }
      }
    }
    return;
  }
  if (MODE==7){                                 // v section (bx 2,3) -> v_p planes (bf16)
    int gm0 = m0 + w*16 + quad*4;
    int b = gm0 / N_, nb = gm0 % N_;            // 4 consecutive rows share b (tiles of 4)
    #pragma unroll
    for (int s=0;s<4;s++){
      int h = (blockIdx.x-2)*2 + (s>>1);
      int d = (s&1)*16 + m;
      bf16 p4[4];
      #pragma unroll
      for (int r=0;r<4;r++) p4[r] = __float2bfloat16(acc[0][s][r] + bias[n0 + s*16 + m]);
      *(s4v*)(aux1 + ((long)(b*NH_+h)*D_ + d)*N_ + nb) = *(const s4v*)p4;
    }
    return;
  }
  // ---- generic epilogue ----
  #pragma unroll
  for (int cc=0; cc<NCH; cc++){
    int m0c = m0 + cc*64;
    #pragma unroll
    for (int s=0;s<4;s++){
      int gn = n0 + s*16 + m;
      #pragma unroll
      for (int r=0;r<4;r++){
        int gm = m0c + w*16 + quad*4 + r;
        if (gm >= M) continue;
        float v = acc[cc][s][r];
        if (MODE==1 || MODE==4 || MODE==6) v += bias[gn];
        else                               v += bias[gm];
        if (MODE==6 && gn >= 384) v = gelu_exact(v);
        if (MODE==4 || MODE==5) v += res[(long)gm*Nn + gn];
        stg(&Cm[(long)gm*Nn + gn], v);
      }
    }
  }
}

// ---------------- MFMA pool-attention PARTIAL (fully LDS-free, all-x32, prefetched) -
// 4 chains/wave, grid (13,8,8) -- verified best (r8 KSP-null, r15 chain-split negative:
// the 4 independent chains ARE the ILP hiding the QK->exp->PV dependency latency).
__global__ __launch_bounds__(256)
void attn_part_kernel(const bf16* __restrict__ qs_, const bf16* __restrict__ kp_,
                      const bf16* __restrict__ vp_,
                      bf16* __restrict__ Op, float* __restrict__ Lp)
{
  int bh = blockIdx.y;
  int z  = blockIdx.z;
  int lane = threadIdx.x & 63;
  int w    = threadIdx.x >> 6;
  int m    = lane & 15, quad = lane >> 4;
  int base = blockIdx.x*256 + w*16;

  s8v af[4]; bool hasQ[4];
  #pragma unroll
  for (int ch=0; ch<4; ch++){
    int qq = base + ch*64;
    hasQ[ch] = (qq < N_);
    af[ch] = *(const s8v*)(qs_ + ((long)bh*N_ + (hasQ[ch] ? qq : base) + m)*D_ + quad*8);
  }
  const bf16* kpb = kp_ + (long)bh*N_*D_;
  const bf16* vpb = vp_ + (long)bh*D_*N_;
  int kperm = (m & 3) + 8*(m >> 2);            // permuted key row for this lane's A-rows
  const f4v CINIT = {-E8L2, -E8L2, -E8L2, -E8L2};
  f4v o0[4], o1[4];
  float l[4];
  #pragma unroll
  for (int ch=0; ch<4; ch++){
    o0[ch] = (f4v){0.f,0.f,0.f,0.f}; o1[ch] = (f4v){0.f,0.f,0.f,0.f};
    l[ch] = 0.f;
  }

  auto loadKV = [&](s8v* kf, s8v* vf, int t){
    kf[0] = *(const s8v*)(kpb + (long)(t + kperm     )*D_ + quad*8);
    kf[1] = *(const s8v*)(kpb + (long)(t + kperm +  4)*D_ + quad*8);
    kf[2] = *(const s8v*)(kpb + (long)(t + kperm + 32)*D_ + quad*8);
    kf[3] = *(const s8v*)(kpb + (long)(t + kperm + 36)*D_ + quad*8);
    vf[0] = *(const s8v*)(vpb + (long)(m     )*N_ + t      + quad*8);
    vf[1] = *(const s8v*)(vpb + (long)(16 + m)*N_ + t      + quad*8);
    vf[2] = *(const s8v*)(vpb + (long)(m     )*N_ + t + 32 + quad*8);
    vf[3] = *(const s8v*)(vpb + (long)(16 + m)*N_ + t + 32 + quad*8);
  };
  auto compute = [&](const s8v* kf, const s8v* vf){
    __builtin_amdgcn_s_setprio(1);
    #pragma unroll
    for (int ch=0; ch<4; ch++){
      f4v c[4];
      #pragma unroll
      for (int s=0;s<4;s++)
        c[s] = __builtin_amdgcn_mfma_f32_16x16x32_bf16(kf[s], af[ch], CINIT, 0, 0, 0);
      bf16 p8a[8], p8b[8];
      float ls = 0.f;
      #pragma unroll
      for (int r=0;r<4;r++){
        float ea = __builtin_amdgcn_exp2f(c[0][r]);   // keys 8q+r
        float eb = __builtin_amdgcn_exp2f(c[1][r]);   // keys 8q+4+r
        float ec = __builtin_amdgcn_exp2f(c[2][r]);   // +32
        float ed = __builtin_amdgcn_exp2f(c[3][r]);
        ls += (ea+eb) + (ec+ed);
        p8a[r] = __float2bfloat16(ea); p8a[4+r] = __float2bfloat16(eb);
        p8b[r] = __float2bfloat16(ec); p8b[4+r] = __float2bfloat16(ed);
      }
      l[ch] += ls;
      s8v pa = *(const s8v*)p8a, pb = *(const s8v*)p8b;
      o0[ch] = __builtin_amdgcn_mfma_f32_16x16x32_bf16(pa, vf[0], o0[ch], 0, 0, 0);
      o1[ch] = __builtin_amdgcn_mfma_f32_16x16x32_bf16(pa, vf[1], o1[ch], 0, 0, 0);
      o0[ch] = __builtin_amdgcn_mfma_f32_16x16x32_bf16(pb, vf[2], o0[ch], 0, 0, 0);
      o1[ch] = __builtin_amdgcn_mfma_f32_16x16x32_bf16(pb, vf[3], o1[ch], 0, 0, 0);
    }
    __builtin_amdgcn_s_setprio(0);
  };

  int tlo = z*SPLIT, thi = (z==KSP-1) ? N_ : tlo + SPLIT;
  s8v kfA[4], vfA[4], kfB[4], vfB[4];
  int t0 = tlo;
  loadKV(kfA, vfA, t0);
  for (;;){
    if (t0 + 64 < thi) loadKV(kfB, vfB, t0 + 64);
    compute(kfA, vfA);
    t0 += 64;
    if (t0 >= thi) break;
    if (t0 + 64 < thi) loadKV(kfA, vfA, t0 + 64);
    compute(kfB, vfB);
    t0 += 64;
    if (t0 >= thi) break;
  }
  // direct per-lane store: lane(m,quad) reg r holds O[q=quad*4+r][d=m] (o0), [16+m] (o1)
  #pragma unroll
  for (int ch=0; ch<4; ch++){
    if (!hasQ[ch]) continue;
    float lr = l[ch];                          // partial for query m over this quad's keys
    lr += __shfl_xor(lr, 16);
    lr += __shfl_xor(lr, 32);                  // full row sum for query m (replicated)
    long gqBase = (long)bh*N_ + base + ch*64;
    #pragma unroll
    for (int r=0;r<4;r++){
      bf16* op = Op + ((long)z*GQ_ + gqBase + quad*4 + r)*32;
      op[m]      = __float2bfloat16(o0[ch][r]);
      op[16 + m] = __float2bfloat16(o1[ch][r]);
    }
    if (quad == 0) Lp[(long)z*GQ_ + gqBase + m] = lr;
  }
}

// ---------------- combine partials + local 3x3 + learnable tokens -> xo rows --------
// 8 lanes per query. r17: fused k cols are PRE-NORMALIZED (gemm6 bx 2,3 epilogue) ->
// the per-neighbor ss/shuffles/sqrt/div are gone; s = dot directly.
__global__ __launch_bounds__(256)
void attn_combine_kernel(const bf16* __restrict__ Op, const float* __restrict__ Lp,
                         const bf16* __restrict__ qs_, const bf16* __restrict__ fused,
                         const float* __restrict__ qe, const float* __restrict__ temp,
                         const float* __restrict__ tokt, const float* __restrict__ tbias,
                         bf16* __restrict__ xo)
{
  int t  = blockIdx.x*256 + threadIdx.x;       // 8 threads per query
  int gq = t >> 3;                             // bh*N + n
  int l8 = t & 7;
  int d0 = l8*4;
  int n = gq % N_; int bh = gq / N_; int h = bh & 3; int b = bh >> 2;
  float out[4] = {0.f,0.f,0.f,0.f};
  // partial-O accumulate (8B per z); Lp: one per lane (KSP == 8-lane group size)
  #pragma unroll
  for (int z=0; z<KSP; z++){
    s4v o4 = *(const s4v*)(Op + ((long)z*GQ_ + gq)*32 + d0);
    #pragma unroll
    for (int j=0;j<4;j++) out[j] += cvt(((const bf16*)&o4)[j]);
  }
  float L = Lp[(long)l8*GQ_ + gq];
  #pragma unroll
  for (int off=1; off<8; off<<=1) L += __shfl_xor(L, off);
  // q chunk (undo the log2e scale baked into qs)
  float q[4];
  {
    s4v q4 = *(const s4v*)(qs_ + (long)gq*D_ + d0);
    #pragma unroll
    for (int j=0;j<4;j++) q[j] = cvt(((const bf16*)&q4)[j]) * 0.6931471805599453f;
  }
  int hy = n / W_, wx = n % W_;
  const bf16* kvb = fused + (long)b*N_*FW + 128 + h*D_ + d0;   // key cols (normalized)
  float el[9];
  #pragma unroll
  for (int k=0;k<9;k++){
    int di = k/3-1, dj = k%3-1;
    int yy = hy+di, xx = wx+dj;
    bool ok = (yy>=0 && yy<H_ && xx>=0 && xx<W_);              // uniform within group
    float dot = 0.f;
    if (ok){
      s4v k4 = *(const s4v*)(kvb + (long)(yy*W_+xx)*FW);
      #pragma unroll
      for (int j=0;j<4;j++)
        dot = fmaf(q[j], cvt(((const bf16*)&k4)[j]), dot);
    }
    #pragma unroll
    for (int off=1; off<8; off<<=1) dot += __shfl_xor(dot, off);
    el[k] = __expf(dot - 8.f);                 // OOB: dot==0 exactly
    L += el[k];
  }
  float invL = 1.f/L;
  #pragma unroll
  for (int j=0;j<4;j++) out[j] *= invL;
  float sp = log1pf(expf(temp[h]));
  float invsp = 1.f/sp;
  float qn[4];
  #pragma unroll
  for (int j=0;j<4;j++) qn[j] = q[j]*invsp - qe[h*D_ + d0 + j];
  const float* tk = tokt + (long)h*9*D_ + d0;
  #pragma unroll
  for (int k=0;k<9;k++){
    f4v tv = *(const f4v*)(tk + k*D_);
    float tok = qn[0]*tv[0] + qn[1]*tv[1] + qn[2]*tv[2] + qn[3]*tv[3];
    #pragma unroll
    for (int off=1; off<8; off<<=1) tok += __shfl_xor(tok, off);
    float wl = tok + tbias[h*9+k] + el[k]*invL;
    int di = k/3-1, dj = k%3-1;
    int yy = hy+di, xx = wx+dj;
    if (yy>=0 && yy<H_ && xx>=0 && xx<W_){                     // OOB v_l -> contributes 0
      s4v v4 = *(const s4v*)(kvb + (long)(yy*W_+xx)*FW + 128);
      #pragma unroll
      for (int j=0;j<4;j++) out[j] = fmaf(wl, cvt(((const bf16*)&v4)[j]), out[j]);
    }
  }
  bf16 o4[4];
  #pragma unroll
  for (int j=0;j<4;j++) o4[j] = __float2bfloat16(out[j]);
  *(s4v*)(xo + ((long)(b*N_ + n))*C_ + h*D_ + d0) = *(const s4v*)o4;
}

// ---------------- depthwise 3x3 + bias + gelu, gated -> g ROWS (n, 352) -------------
__global__ __launch_bounds__(256)
void dwconv_kernel(const bf16* __restrict__ f1, const float* __restrict__ dww,
                   const float* __restrict__ dwb, bf16* __restrict__ g)
{
  __shared__ bf16 sg[32*72];                   // 32 c x 64 n, stride 72 (4-way on write)
  int bx = blockIdx.x;                         // ((b*11 + cg)*49 + ntile)
  int ntile = bx % 49;
  int cg    = (bx / 49) % 11;
  int b     = bx / (49*11);
  int t = threadIdx.x;
  f1 += (long)b*2*HF_*N_;
  {
    int c_local = t & 31, chun = t >> 5;
    int c = cg*32 + c_local;
    int n0 = ntile*64 + chun*8;
    int y = n0 / W_, x0 = n0 % W_;             // chunks never cross rows (8 | 56)
    bf16 o8[8];
    if (c < HF_){
      const bf16* ap = f1 + (long)c*N_;
      float acc[8];
      #pragma unroll
      for (int j=0;j<8;j++) acc[j] = dwb[c];
      #pragma unroll
      for (int dy=-1; dy<=1; dy++){
        int yy = y + dy;
        if (yy < 0 || yy >= H_) continue;
        int base = yy*W_ + x0;
        s8v mid = *(const s8v*)(ap + base);    // 16B aligned (112|yy*W_*2, 16|x0*2)
        float wnd[10];
        wnd[0] = (x0 > 0)      ? cvt(ap[base-1]) : 0.f;
        #pragma unroll
        for (int j=0;j<8;j++) wnd[1+j] = cvt(((const bf16*)&mid)[j]);
        wnd[9] = (x0 + 8 < W_) ? cvt(ap[base+8]) : 0.f;
        float k0 = dww[c*9 + (dy+1)*3    ];
        float k1 = dww[c*9 + (dy+1)*3 + 1];
        float k2 = dww[c*9 + (dy+1)*3 + 2];
        #pragma unroll
        for (int j=0;j<8;j++)
          acc[j] = fmaf(k0, wnd[j], fmaf(k1, wnd[j+1], fmaf(k2, wnd[j+2], acc[j])));
      }
      s8v g8 = *(const s8v*)(f1 + (long)(HF_+c)*N_ + n0);
      #pragma unroll
      for (int j=0;j<8;j++)
        o8[j] = __float2bfloat16(gelu_exact(acc[j]) * cvt(((const bf16*)&g8)[j]));
    } else {
      #pragma unroll
      for (int j=0;j<8;j++) o8[j] = __float2bfloat16(0.f);
    }
    *(s8v*)(&sg[c_local*72 + chun*8]) = *(const s8v*)o8;
  }
  __syncthreads();
  {
    int n_local = t >> 2, c0 = (t & 3)*8;
    bf16 o8[8];
    #pragma unroll
    for (int j=0;j<8;j++) o8[j] = sg[(c0+j)*72 + n_local];
    *(s8v*)(g + (long)b*N_*KF2 + (long)(ntile*64 + n_local)*KF2 + cg*32 + c0)
        = *(const s8v*)o8;
  }
}

// ---------------- launcher ----------------
extern "C" void kernel_launch(void* const* d_in, const int* in_sizes, int n_in,
                              void* d_out, int out_size, void* d_ws, size_t ws_size,
                              hipStream_t stream)
{
  (void)in_sizes; (void)n_in; (void)out_size; (void)ws_size;
  const float* x_in      = (const float*)d_in[0];
  const float* norm1_w   = (const float*)d_in[1];
  const float* norm1_b   = (const float*)d_in[2];
  const float* q_w       = (const float*)d_in[3];
  const float* q_b       = (const float*)d_in[4];
  const float* kv_w      = (const float*)d_in[5];
  const float* kv_b      = (const float*)d_in[6];
  const float* temp      = (const float*)d_in[7];
  const float* qe        = (const float*)d_in[8];
  const float* tokens    = (const float*)d_in[9];
  const float* tbias     = (const float*)d_in[10];
  const float* sr_w      = (const float*)d_in[11];
  const float* sr_b      = (const float*)d_in[12];
  const float* pln_w     = (const float*)d_in[13];
  const float* pln_b     = (const float*)d_in[14];
  const float* proj_w    = (const float*)d_in[15];
  const float* proj_b    = (const float*)d_in[16];
  const float* norm2_w   = (const float*)d_in[17];
  const float* norm2_b   = (const float*)d_in[18];
  const float* fc1_w     = (const float*)d_in[19];
  const float* fc1_b     = (const float*)d_in[20];
  const float* dw_w      = (const float*)d_in[21];
  const float* dw_b      = (const float*)d_in[22];
  const float* fc2_w     = (const float*)d_in[23];
  const float* fc2_b     = (const float*)d_in[24];

  char* w8 = (char*)d_ws;
  bf16*  fused   = (bf16*)(w8 + 0);
  float* x2      = (float*)(w8 + 0);
  bf16*  y2      = (bf16*)(w8 + 3211264);
  bf16*  f1b     = (bf16*)(w8 + 4816896);
  bf16*  qs      = (bf16*)(w8 + 6422528);
  bf16*  k_p     = (bf16*)(w8 + 9633792);
  bf16*  v_p     = (bf16*)(w8 + 11239424);
  bf16*  Opart   = (bf16*)(w8 + 13045056);
  bf16*  g_rows  = (bf16*)(w8 + 32312640);
  bf16*  wbase   = (bf16*)(w8 + 36728128);
  float* fbias   = (float*)(w8 + 37156672);
  float* tokt    = (float*)(w8 + 37158720);
  bf16*  y       = f1b;                         // LN1 output rows (dead before f1b use)
  bf16*  xo      = (bf16*)d_out;
  float* Lpart   = (float*)((char*)d_out + 1605632);
  bf16*  proj_wb = wbase + 65536;
  bf16*  fc1_wb  = wbase + 81920;
  bf16*  fc2_wb  = wbase + 169216;

  // 0. weights -> bf16 (vectorized) + bias + tokens^T + tiled LN1 (216+392 blocks)
  head_kernel<<<216 + NTILE, 256, 0, stream>>>(
      q_w, kv_w, sr_w, proj_w, fc1_w, fc2_w, q_b, kv_b, sr_b, tokens,
      wbase, fbias, tokt, x_in, norm1_w, norm1_b, y);
  // 2. fused = y @ [q_w; kv_w; sr_w]^T + bias; q cols -> qs; k cols l2-normalized
  //    in-place (r17); v cols plain; sr cols gelu'd.
  gemm_mfma<128, 6, bf16, 128, 128, 2><<<dim3(8,49), 256, 0, stream>>>(
      y, wbase, fbias, nullptr, fused, ROWS_, FW, 0,0,0,0, qe, temp, qs, nullptr);
  // 4. kvp = LN_pln(fused sr cols) @ kv_w^T + kv_b
  gemm_mfma<128, 7, bf16, 64, FW><<<dim3(4,98), 256, 0, stream>>>(
      fused + 384, wbase + 16384, kv_b, nullptr, (bf16*)nullptr, ROWS_, 256, 0,0,0,0,
      pln_w, pln_b, k_p, v_p);
  // 5. pool-attention partials (4 chains/wave, grid (13,8,8) -- verified best)
  attn_part_kernel<<<dim3(13,8,KSP), 256, 0, stream>>>(qs, k_p, v_p, Opart, Lpart);
  // 6. combine + local 3x3 + tokens -> xo
  attn_combine_kernel<<<GQ_*8/256, 256, 0, stream>>>(Opart, Lpart, qs, fused,
                                                     qe, temp, tokt, tbias, xo);
  // 7. x2 = x_in + (xo @ proj_w^T + proj_b)
  gemm_mfma<128, 4, float, 16><<<dim3(2,392), 64, 0, stream>>>(
      xo, proj_wb, proj_b, x_in, x2, ROWS_, 128, 0,0,0,0, nullptr, nullptr, nullptr, nullptr);
  // 8. y2 = LN2(x2)
  ln_tile_kernel<<<NTILE, 256, 0, stream>>>(x2, norm2_w, norm2_b, y2);
  // 9. MLP
  gemm_mfma<128, 3, bf16, 128, 128, 2><<<dim3(49,6,B_), 256, 0, stream>>>(
      fc1_wb, y2, fc1_b, nullptr, f1b, 2*HF_, N_,
      0, (long)N_*C_, (long)2*HF_*N_, 0, nullptr, nullptr, nullptr, nullptr);
  dwconv_kernel<<<B_*11*49, 256, 0, stream>>>(f1b, dw_w, dw_b, g_rows);
  gemm_mfma<KF2, 5, float, 16><<<dim3(49,8,B_), 64, 0, stream>>>(
      fc2_wb, g_rows, fc2_b, x2, (float*)d_out, C_, N_,
      0, (long)N_*KF2, (long)C_*N_, (long)C_*N_, nullptr, nullptr, nullptr, nullptr);
}